// Round 1
// baseline (863.775 us; speedup 1.0000x reference)
//
#include <hip/hip_runtime.h>
#include <math.h>

#define Nn 4096
#define Ee 384
#define Hh 6
#define DHh 64
#define MIDm 96
#define TEe 1152

#define QT 32
#define KT 64
#define PADp 65

__device__ __forceinline__ float gelu_exact(float x) {
    return 0.5f * x * (1.0f + erff(x * 0.70710678118654752f));
}
__device__ __forceinline__ float sigmoidf_(float x) {
    return 1.0f / (1.0f + __expf(-x));
}

// ---------------- kernel 0: sum(ref_w) ----------------
__global__ __launch_bounds__(256) void k_wsum(const float* __restrict__ rw,
                                              float* __restrict__ wsum) {
    __shared__ float red[4];
    const int t = threadIdx.x;
    float s = 0.0f;
    for (int i = t; i < Nn; i += 256) s += rw[i];
#pragma unroll
    for (int off = 32; off > 0; off >>= 1) s += __shfl_down(s, off, 64);
    if ((t & 63) == 0) red[t >> 6] = s;
    __syncthreads();
    if (t == 0) {
        float a = 0.0f;
#pragma unroll
        for (int w = 0; w < 4; w++) a += red[w];
        wsum[0] = a;
    }
}

// ---------------- kernel 1: dual channel-MLP + layer fuse ----------------
// grid Nn/4 blocks x 384 threads; 4 rows per block
__global__ __launch_bounds__(384) void k_fused(
    const float* __restrict__ low, const float* __restrict__ high,
    const float* __restrict__ lf,
    const float* __restrict__ lw1, const float* __restrict__ lb1,
    const float* __restrict__ lw2, const float* __restrict__ lb2,
    const float* __restrict__ hw1, const float* __restrict__ hb1,
    const float* __restrict__ hw2, const float* __restrict__ hb2,
    float* __restrict__ fused) {
    __shared__ float xl[4][Ee], xh[4][Ee];
    __shared__ float hl[4][MIDm], hh[4][MIDm];
    const int t = threadIdx.x;
    const int n0 = blockIdx.x * 4;
#pragma unroll
    for (int r = 0; r < 4; r++) {
        xl[r][t] = low[(size_t)(n0 + r) * Ee + t];
        xh[r][t] = high[(size_t)(n0 + r) * Ee + t];
    }
    __syncthreads();
    // stage 1: h = gelu(x @ w1 + b1), split low/high across wave-aligned thread groups
    int role = -1, m = 0;
    if (t < MIDm) { role = 0; m = t; }
    else if (t >= 192 && t < 192 + MIDm) { role = 1; m = t - 192; }
    if (role >= 0) {
        const float* w1p = role ? hw1 : lw1;
        const float* b1p = role ? hb1 : lb1;
        const float (*xs)[Ee] = role ? xh : xl;
        float a[4];
        float bb = b1p[m];
#pragma unroll
        for (int r = 0; r < 4; r++) a[r] = bb;
        for (int e = 0; e < Ee; e++) {
            float w = w1p[e * MIDm + m];
#pragma unroll
            for (int r = 0; r < 4; r++) a[r] += xs[r][e] * w;
        }
        float (*ho)[MIDm] = role ? hh : hl;
#pragma unroll
        for (int r = 0; r < 4; r++) ho[r][m] = gelu_exact(a[r]);
    }
    __syncthreads();
    // stage 2: s = h @ w2 + b2 ; out = x * sigmoid(s); fuse
    float sL[4], sH[4];
    const float bl2 = lb2[t], bh2 = hb2[t];
#pragma unroll
    for (int r = 0; r < 4; r++) { sL[r] = bl2; sH[r] = bh2; }
    for (int mm = 0; mm < MIDm; mm++) {
        float wl = lw2[mm * Ee + t];
        float wh = hw2[mm * Ee + t];
#pragma unroll
        for (int r = 0; r < 4; r++) {
            sL[r] += hl[r][mm] * wl;
            sH[r] += hh[r][mm] * wh;
        }
    }
    const float a0 = lf[0], a1 = lf[1];
    const float mx = fmaxf(a0, a1);
    const float e0 = __expf(a0 - mx), e1 = __expf(a1 - mx);
    const float inv = 1.0f / (e0 + e1);
    const float w0 = e0 * inv, w1v = e1 * inv;
#pragma unroll
    for (int r = 0; r < 4; r++) {
        float fl = xl[r][t] * sigmoidf_(sL[r]);
        float fh = xh[r][t] * sigmoidf_(sH[r]);
        fused[(size_t)(n0 + r) * Ee + t] = w0 * fl + w1v * fh;
    }
}

// ---------------- kernel 2: qkv projection ----------------
// grid Nn/8 x 384 threads; writes q/k/v as [H][N][DH]; q pre-scaled by 1/sqrt(DH)
__global__ __launch_bounds__(384) void k_qkv(
    const float* __restrict__ fused, const float* __restrict__ wqkv,
    const float* __restrict__ bqkv,
    float* __restrict__ q, float* __restrict__ kk, float* __restrict__ vv) {
    __shared__ float xs[8][Ee];
    const int t = threadIdx.x;
    const int n0 = blockIdx.x * 8;
#pragma unroll
    for (int r = 0; r < 8; r++) xs[r][t] = fused[(size_t)(n0 + r) * Ee + t];
    __syncthreads();
    float aq[8], ak[8], av[8];
    const float bq = bqkv[t], bk = bqkv[Ee + t], bv = bqkv[2 * Ee + t];
#pragma unroll
    for (int r = 0; r < 8; r++) { aq[r] = bq; ak[r] = bk; av[r] = bv; }
    for (int e = 0; e < Ee; e++) {
        const float wq = wqkv[(size_t)e * TEe + t];
        const float wk = wqkv[(size_t)e * TEe + Ee + t];
        const float wv = wqkv[(size_t)e * TEe + 2 * Ee + t];
#pragma unroll
        for (int r = 0; r < 8; r++) {
            float x = xs[r][e];
            aq[r] += x * wq; ak[r] += x * wk; av[r] += x * wv;
        }
    }
    const int h = t / DHh, d = t % DHh;
#pragma unroll
    for (int r = 0; r < 8; r++) {
        size_t idx = ((size_t)h * Nn + (n0 + r)) * DHh + d;
        q[idx] = aq[r] * 0.125f;
        kk[idx] = ak[r];
        vv[idx] = av[r];
    }
}

// ---------------- kernel 3: flash attention (f32) ----------------
// grid (Nn/QT, Hh) x 128 threads; 4q x 4k register micro-tiles
__global__ __launch_bounds__(128) void k_attn(
    const float* __restrict__ q, const float* __restrict__ k,
    const float* __restrict__ v, float* __restrict__ ctx) {
    __shared__ float Qs[QT][PADp], Ks[KT][PADp], Vs[KT][PADp], Ps[QT][PADp];
    const int t = threadIdx.x;
    const int h = blockIdx.y;
    const int qt = blockIdx.x;
    const float* qh = q + (size_t)h * Nn * DHh;
    const float* kh = k + (size_t)h * Nn * DHh;
    const float* vh = v + (size_t)h * Nn * DHh;
    for (int i = t; i < QT * DHh; i += 128)
        Qs[i >> 6][i & 63] = qh[(size_t)(qt * QT + (i >> 6)) * DHh + (i & 63)];
    const int qg = t >> 4, kg = t & 15;  // phase B reuses kg as the d-group
    float o[4][4];
    float mreg[4], lreg[4];
#pragma unroll
    for (int i = 0; i < 4; i++) {
        mreg[i] = -1e30f; lreg[i] = 0.0f;
#pragma unroll
        for (int j = 0; j < 4; j++) o[i][j] = 0.0f;
    }
    for (int kt = 0; kt < Nn / KT; kt++) {
        __syncthreads();  // protect Ks/Vs from previous iteration readers
        for (int i = t; i < KT * DHh; i += 128) {
            int r = i >> 6, c = i & 63;
            size_t gidx = (size_t)(kt * KT + r) * DHh + c;
            Ks[r][c] = kh[gidx];
            Vs[r][c] = vh[gidx];
        }
        __syncthreads();
        // phase A: S = Q K^T (q pre-scaled)
        float s[4][4];
#pragma unroll
        for (int i = 0; i < 4; i++)
#pragma unroll
            for (int j = 0; j < 4; j++) s[i][j] = 0.0f;
        for (int d = 0; d < DHh; d++) {
            float qv[4], kv[4];
#pragma unroll
            for (int i = 0; i < 4; i++) qv[i] = Qs[qg * 4 + i][d];
#pragma unroll
            for (int j = 0; j < 4; j++) kv[j] = Ks[kg * 4 + j][d];
#pragma unroll
            for (int i = 0; i < 4; i++)
#pragma unroll
                for (int j = 0; j < 4; j++) s[i][j] += qv[i] * kv[j];
        }
        // online softmax: stats replicated across the 16 lanes of each row group
        float scl[4];
#pragma unroll
        for (int i = 0; i < 4; i++) {
            const int row = qg * 4 + i;
            float mloc = fmaxf(fmaxf(s[i][0], s[i][1]), fmaxf(s[i][2], s[i][3]));
#pragma unroll
            for (int off = 1; off < 16; off <<= 1)
                mloc = fmaxf(mloc, __shfl_xor(mloc, off, 64));
            const float mold = mreg[i];
            const float mnew = fmaxf(mold, mloc);
            float ssum = 0.0f;
#pragma unroll
            for (int j = 0; j < 4; j++) {
                float p = __expf(s[i][j] - mnew);
                Ps[row][kg * 4 + j] = p;
                ssum += p;
            }
#pragma unroll
            for (int off = 1; off < 16; off <<= 1)
                ssum += __shfl_xor(ssum, off, 64);
            const float sc = __expf(mold - mnew);
            mreg[i] = mnew;
            lreg[i] = lreg[i] * sc + ssum;
            scl[i] = sc;
        }
        // phase B: O = O*scale + P V   (P rows are wave-private; no barrier needed)
#pragma unroll
        for (int i = 0; i < 4; i++)
#pragma unroll
            for (int j = 0; j < 4; j++) o[i][j] *= scl[i];
        for (int kk2 = 0; kk2 < KT; kk2++) {
            float pv[4], vv2[4];
#pragma unroll
            for (int i = 0; i < 4; i++) pv[i] = Ps[qg * 4 + i][kk2];
#pragma unroll
            for (int j = 0; j < 4; j++) vv2[j] = Vs[kk2][kg * 4 + j];
#pragma unroll
            for (int i = 0; i < 4; i++)
#pragma unroll
                for (int j = 0; j < 4; j++) o[i][j] += pv[i] * vv2[j];
        }
    }
#pragma unroll
    for (int i = 0; i < 4; i++) {
        const float inv = 1.0f / lreg[i];
        const int row = qt * QT + qg * 4 + i;
#pragma unroll
        for (int j = 0; j < 4; j++)
            ctx[(size_t)row * Ee + h * DHh + kg * 4 + j] = o[i][j] * inv;
    }
}

// ---------------- kernel 4: out-proj + residual + LN + weighted partials ----------------
// grid Nn/8 x 384 threads
__global__ __launch_bounds__(384) void k_out(
    const float* __restrict__ ctx, const float* __restrict__ fused,
    const float* __restrict__ wo, const float* __restrict__ bo,
    const float* __restrict__ lng, const float* __restrict__ lnb,
    const float* __restrict__ rw, const float* __restrict__ wsum_p,
    float* __restrict__ part) {
    __shared__ float cs[8][Ee];
    __shared__ float red1[6], red2[6];
    const int t = threadIdx.x;
    const int n0 = blockIdx.x * 8;
#pragma unroll
    for (int r = 0; r < 8; r++) cs[r][t] = ctx[(size_t)(n0 + r) * Ee + t];
    __syncthreads();
    float acc[8];
    const float bt = bo[t];
#pragma unroll
    for (int r = 0; r < 8; r++) acc[r] = bt;
    for (int e = 0; e < Ee; e++) {
        const float w = wo[(size_t)e * Ee + t];
#pragma unroll
        for (int r = 0; r < 8; r++) acc[r] += cs[r][e] * w;
    }
    const float gt = lng[t], bb = lnb[t];
    const float winv = 1.0f / wsum_p[0];
    const int wid = t >> 6, lane = t & 63;
    float outacc = 0.0f;
    for (int r = 0; r < 8; r++) {
        const float x = acc[r] + fused[(size_t)(n0 + r) * Ee + t];
        float s1 = x, s2 = x * x;
#pragma unroll
        for (int off = 32; off > 0; off >>= 1) {
            s1 += __shfl_down(s1, off, 64);
            s2 += __shfl_down(s2, off, 64);
        }
        if (lane == 0) { red1[wid] = s1; red2[wid] = s2; }
        __syncthreads();
        float ts1 = 0.0f, ts2 = 0.0f;
#pragma unroll
        for (int w2 = 0; w2 < 6; w2++) { ts1 += red1[w2]; ts2 += red2[w2]; }
        __syncthreads();
        const float mu = ts1 * (1.0f / Ee);
        const float var = ts2 * (1.0f / Ee) - mu * mu;
        const float xn = (x - mu) * rsqrtf(var + 1e-5f) * gt + bb;
        outacc += xn * (rw[n0 + r] * winv);
    }
    part[(size_t)blockIdx.x * Ee + t] = outacc;
}

// ---------------- kernel 5: ordered partial reduce + L2 normalize ----------------
__global__ __launch_bounds__(384) void k_final(const float* __restrict__ part,
                                               float* __restrict__ outp) {
    __shared__ float red[6];
    const int t = threadIdx.x;
    float s = 0.0f;
    for (int b = 0; b < Nn / 8; b++) s += part[(size_t)b * Ee + t];
    float q2 = s * s;
#pragma unroll
    for (int off = 32; off > 0; off >>= 1) q2 += __shfl_down(q2, off, 64);
    const int wid = t >> 6, lane = t & 63;
    if (lane == 0) red[wid] = q2;
    __syncthreads();
    float tot = 0.0f;
#pragma unroll
    for (int w = 0; w < 6; w++) tot += red[w];
    outp[t] = s / (sqrtf(tot) + 1e-8f);
}

extern "C" void kernel_launch(void* const* d_in, const int* in_sizes, int n_in,
                              void* d_out, int out_size, void* d_ws, size_t ws_size,
                              hipStream_t stream) {
    const float* low  = (const float*)d_in[0];
    const float* high = (const float*)d_in[1];
    const float* rw   = (const float*)d_in[2];
    const float* lw1  = (const float*)d_in[3];
    const float* lb1  = (const float*)d_in[4];
    const float* lw2  = (const float*)d_in[5];
    const float* lb2  = (const float*)d_in[6];
    const float* hw1  = (const float*)d_in[7];
    const float* hb1  = (const float*)d_in[8];
    const float* hw2  = (const float*)d_in[9];
    const float* hb2  = (const float*)d_in[10];
    const float* lf   = (const float*)d_in[11];
    const float* wqkv = (const float*)d_in[12];
    const float* bqkv = (const float*)d_in[13];
    const float* wo   = (const float*)d_in[14];
    const float* bo   = (const float*)d_in[15];
    const float* lng  = (const float*)d_in[16];
    const float* lnb  = (const float*)d_in[17];

    float* ws    = (float*)d_ws;
    const size_t NE = (size_t)Nn * Ee;
    float* fused = ws;
    float* q     = ws + NE;
    float* kk    = ws + 2 * NE;
    float* vv    = ws + 3 * NE;
    float* ctx   = ws + 4 * NE;
    float* part  = ws + 5 * NE;           // (Nn/8) * Ee
    float* wsum  = part + (size_t)(Nn / 8) * Ee;

    hipLaunchKernelGGL(k_wsum, dim3(1), dim3(256), 0, stream, rw, wsum);
    hipLaunchKernelGGL(k_fused, dim3(Nn / 4), dim3(384), 0, stream,
                       low, high, lf, lw1, lb1, lw2, lb2, hw1, hb1, hw2, hb2, fused);
    hipLaunchKernelGGL(k_qkv, dim3(Nn / 8), dim3(384), 0, stream,
                       fused, wqkv, bqkv, q, kk, vv);
    hipLaunchKernelGGL(k_attn, dim3(Nn / QT, Hh), dim3(128), 0, stream, q, kk, vv, ctx);
    hipLaunchKernelGGL(k_out, dim3(Nn / 8), dim3(384), 0, stream,
                       ctx, fused, wo, bo, lng, lnb, rw, wsum, part);
    hipLaunchKernelGGL(k_final, dim3(1), dim3(384), 0, stream, part, (float*)d_out);
}

// Round 2
// 368.228 us; speedup vs baseline: 2.3458x; 2.3458x over previous
//
#include <hip/hip_runtime.h>
#include <math.h>

#define Nn 4096
#define Ee 384
#define Hh 6
#define DHh 64
#define MIDm 96
#define TEe 1152

typedef short s16x8 __attribute__((ext_vector_type(8)));
typedef float f32x4 __attribute__((ext_vector_type(4)));
typedef unsigned short ushort_t;

__device__ __forceinline__ float gelu_exact(float x) {
    return 0.5f * x * (1.0f + erff(x * 0.70710678118654752f));
}
__device__ __forceinline__ float sigmoidf_(float x) {
    return 1.0f / (1.0f + __expf(-x));
}
__device__ __forceinline__ ushort_t f2bf(float x) {
    unsigned int u = __float_as_uint(x);
    u = (u + 0x7FFFu + ((u >> 16) & 1u)) >> 16;
    return (ushort_t)u;
}

// ---------------- kernel 0: sum(ref_w) ----------------
__global__ __launch_bounds__(256) void k_wsum(const float* __restrict__ rw,
                                              float* __restrict__ wsum) {
    __shared__ float red[4];
    const int t = threadIdx.x;
    float s = 0.0f;
    for (int i = t; i < Nn; i += 256) s += rw[i];
#pragma unroll
    for (int off = 32; off > 0; off >>= 1) s += __shfl_down(s, off, 64);
    if ((t & 63) == 0) red[t >> 6] = s;
    __syncthreads();
    if (t == 0) {
        float a = 0.0f;
#pragma unroll
        for (int w = 0; w < 4; w++) a += red[w];
        wsum[0] = a;
    }
}

// ---------------- kernel 1: dual channel-MLP + layer fuse ----------------
__global__ __launch_bounds__(384) void k_fused(
    const float* __restrict__ low, const float* __restrict__ high,
    const float* __restrict__ lf,
    const float* __restrict__ lw1, const float* __restrict__ lb1,
    const float* __restrict__ lw2, const float* __restrict__ lb2,
    const float* __restrict__ hw1, const float* __restrict__ hb1,
    const float* __restrict__ hw2, const float* __restrict__ hb2,
    float* __restrict__ fused) {
    __shared__ float xl[4][Ee], xh[4][Ee];
    __shared__ float hl[4][MIDm], hh[4][MIDm];
    const int t = threadIdx.x;
    const int n0 = blockIdx.x * 4;
#pragma unroll
    for (int r = 0; r < 4; r++) {
        xl[r][t] = low[(size_t)(n0 + r) * Ee + t];
        xh[r][t] = high[(size_t)(n0 + r) * Ee + t];
    }
    __syncthreads();
    int role = -1, m = 0;
    if (t < MIDm) { role = 0; m = t; }
    else if (t >= 192 && t < 192 + MIDm) { role = 1; m = t - 192; }
    if (role >= 0) {
        const float* w1p = role ? hw1 : lw1;
        const float* b1p = role ? hb1 : lb1;
        const float (*xs)[Ee] = role ? xh : xl;
        float a[4];
        float bb = b1p[m];
#pragma unroll
        for (int r = 0; r < 4; r++) a[r] = bb;
        for (int e = 0; e < Ee; e++) {
            float w = w1p[e * MIDm + m];
#pragma unroll
            for (int r = 0; r < 4; r++) a[r] += xs[r][e] * w;
        }
        float (*ho)[MIDm] = role ? hh : hl;
#pragma unroll
        for (int r = 0; r < 4; r++) ho[r][m] = gelu_exact(a[r]);
    }
    __syncthreads();
    float sL[4], sH[4];
    const float bl2 = lb2[t], bh2 = hb2[t];
#pragma unroll
    for (int r = 0; r < 4; r++) { sL[r] = bl2; sH[r] = bh2; }
    for (int mm = 0; mm < MIDm; mm++) {
        float wl = lw2[mm * Ee + t];
        float wh = hw2[mm * Ee + t];
#pragma unroll
        for (int r = 0; r < 4; r++) {
            sL[r] += hl[r][mm] * wl;
            sH[r] += hh[r][mm] * wh;
        }
    }
    const float a0 = lf[0], a1 = lf[1];
    const float mx = fmaxf(a0, a1);
    const float e0 = __expf(a0 - mx), e1 = __expf(a1 - mx);
    const float inv = 1.0f / (e0 + e1);
    const float w0 = e0 * inv, w1v = e1 * inv;
#pragma unroll
    for (int r = 0; r < 4; r++) {
        float fl = xl[r][t] * sigmoidf_(sL[r]);
        float fh = xh[r][t] * sigmoidf_(sH[r]);
        fused[(size_t)(n0 + r) * Ee + t] = w0 * fl + w1v * fh;
    }
}

// ---------------- kernel 2: qkv projection -> bf16 q,k,[H][N][64]; v transposed [H][64][N] ----------------
__global__ __launch_bounds__(384) void k_qkv(
    const float* __restrict__ fused, const float* __restrict__ wqkv,
    const float* __restrict__ bqkv,
    ushort_t* __restrict__ q, ushort_t* __restrict__ kk, ushort_t* __restrict__ vt) {
    __shared__ float xs[8][Ee];
    const int t = threadIdx.x;
    const int n0 = blockIdx.x * 8;
#pragma unroll
    for (int r = 0; r < 8; r++) xs[r][t] = fused[(size_t)(n0 + r) * Ee + t];
    __syncthreads();
    float aq[8], ak[8], av[8];
    const float bq = bqkv[t], bk = bqkv[Ee + t], bv = bqkv[2 * Ee + t];
#pragma unroll
    for (int r = 0; r < 8; r++) { aq[r] = bq; ak[r] = bk; av[r] = bv; }
    for (int e = 0; e < Ee; e++) {
        const float wq = wqkv[(size_t)e * TEe + t];
        const float wk = wqkv[(size_t)e * TEe + Ee + t];
        const float wv = wqkv[(size_t)e * TEe + 2 * Ee + t];
#pragma unroll
        for (int r = 0; r < 8; r++) {
            float x = xs[r][e];
            aq[r] += x * wq; ak[r] += x * wk; av[r] += x * wv;
        }
    }
    const int h = t / DHh, d = t % DHh;
#pragma unroll
    for (int r = 0; r < 8; r++) {
        size_t idx = ((size_t)h * Nn + (n0 + r)) * DHh + d;
        q[idx] = f2bf(aq[r] * 0.125f);
        kk[idx] = f2bf(ak[r]);
        vt[((size_t)h * DHh + d) * Nn + (n0 + r)] = f2bf(av[r]);
    }
}

// ---------------- kernel 3: flash attention, bf16 MFMA ----------------
// grid (Nn/32, Hh) x 128 threads (2 waves); wave handles 16 q-rows; KV tile = 64
#define KVB 64
#define LP 72  // padded row length (bf16 elems): 144B stride -> conflict-free b128
__global__ __launch_bounds__(128) void k_attn(
    const ushort_t* __restrict__ q, const ushort_t* __restrict__ k,
    const ushort_t* __restrict__ vt, float* __restrict__ ctx) {
    __shared__ ushort_t Kt[KVB][LP];
    __shared__ ushort_t VtT[DHh][LP];
    __shared__ ushort_t Pt[2][16][LP];
    const int t = threadIdx.x;
    const int wid = t >> 6;
    const int l = t & 63;
    const int g = l >> 4;    // k-slice group (0..3)
    const int c = l & 15;    // row/col within fragment
    const int h = blockIdx.y;
    const int qt = blockIdx.x;
    const ushort_t* qh = q + (size_t)h * Nn * DHh;
    const ushort_t* kh = k + (size_t)h * Nn * DHh;
    const ushort_t* vth = vt + (size_t)h * DHh * Nn;

    // Q fragments (A operand), rows qt*32 + wid*16 + c, k-slices g*8
    s16x8 qf[2];
#pragma unroll
    for (int kc = 0; kc < 2; kc++) {
        const int row = qt * 32 + wid * 16 + c;
        qf[kc] = *(const s16x8*)(qh + (size_t)row * DHh + kc * 32 + g * 8);
    }

    f32x4 o[4];
    float mreg[4], lreg[4];
#pragma unroll
    for (int r = 0; r < 4; r++) { mreg[r] = -1e30f; lreg[r] = 0.0f; }
#pragma unroll
    for (int cb = 0; cb < 4; cb++) o[cb] = (f32x4){0.f, 0.f, 0.f, 0.f};

    for (int kt = 0; kt < Nn / KVB; kt++) {
        __syncthreads();  // previous iteration's readers done
        // stage K tile [64 kv][64 dh] and V^T tile [64 dh][64 kv]
        for (int i = t; i < KVB * 8; i += 128) {
            const int row = i >> 3, seg = i & 7;
            *(s16x8*)&Kt[row][seg * 8] =
                *(const s16x8*)(kh + (size_t)(kt * KVB + row) * DHh + seg * 8);
            *(s16x8*)&VtT[row][seg * 8] =
                *(const s16x8*)(vth + (size_t)row * Nn + kt * KVB + seg * 8);
        }
        __syncthreads();
        // S = Q K^T  (4 col-blocks x 2 k-chunks)
        f32x4 sacc[4];
#pragma unroll
        for (int cb = 0; cb < 4; cb++) sacc[cb] = (f32x4){0.f, 0.f, 0.f, 0.f};
#pragma unroll
        for (int kc = 0; kc < 2; kc++) {
#pragma unroll
            for (int cb = 0; cb < 4; cb++) {
                s16x8 bK = *(const s16x8*)&Kt[cb * 16 + c][kc * 32 + g * 8];
                sacc[cb] = __builtin_amdgcn_mfma_f32_16x16x32_bf16(qf[kc], bK, sacc[cb], 0, 0, 0);
            }
        }
        // online softmax; lane holds rows m=4g+r, cols c of each col-block
        float scl[4];
#pragma unroll
        for (int r = 0; r < 4; r++) {
            float mx = fmaxf(fmaxf(sacc[0][r], sacc[1][r]), fmaxf(sacc[2][r], sacc[3][r]));
#pragma unroll
            for (int off = 1; off < 16; off <<= 1)
                mx = fmaxf(mx, __shfl_xor(mx, off, 64));
            const float mnew = fmaxf(mreg[r], mx);
            scl[r] = __expf(mreg[r] - mnew);
            mreg[r] = mnew;
            float ss = 0.0f;
#pragma unroll
            for (int cb = 0; cb < 4; cb++) {
                float p = __expf(sacc[cb][r] - mnew);
                ss += p;
                Pt[wid][4 * g + r][cb * 16 + c] = f2bf(p);
            }
#pragma unroll
            for (int off = 1; off < 16; off <<= 1)
                ss += __shfl_xor(ss, off, 64);
            lreg[r] = lreg[r] * scl[r] + ss;
        }
#pragma unroll
        for (int cb = 0; cb < 4; cb++)
#pragma unroll
            for (int r = 0; r < 4; r++) o[cb][r] *= scl[r];
        // O += P V  (wave-private Pt; DS ops in-order per wave -> no barrier)
#pragma unroll
        for (int kc = 0; kc < 2; kc++) {
            s16x8 aP = *(const s16x8*)&Pt[wid][c][kc * 32 + g * 8];
#pragma unroll
            for (int cb = 0; cb < 4; cb++) {
                s16x8 bV = *(const s16x8*)&VtT[cb * 16 + c][kc * 32 + g * 8];
                o[cb] = __builtin_amdgcn_mfma_f32_16x16x32_bf16(aP, bV, o[cb], 0, 0, 0);
            }
        }
    }
#pragma unroll
    for (int r = 0; r < 4; r++) {
        const float inv = 1.0f / lreg[r];
        const int row = qt * 32 + wid * 16 + 4 * g + r;
#pragma unroll
        for (int cb = 0; cb < 4; cb++)
            ctx[(size_t)row * Ee + h * DHh + cb * 16 + c] = o[cb][r] * inv;
    }
}

// ---------------- kernel 4: out-proj + residual + LN + weighted partials ----------------
__global__ __launch_bounds__(384) void k_out(
    const float* __restrict__ ctx, const float* __restrict__ fused,
    const float* __restrict__ wo, const float* __restrict__ bo,
    const float* __restrict__ lng, const float* __restrict__ lnb,
    const float* __restrict__ rw, const float* __restrict__ wsum_p,
    float* __restrict__ part) {
    __shared__ float cs[8][Ee];
    __shared__ float red1[6], red2[6];
    const int t = threadIdx.x;
    const int n0 = blockIdx.x * 8;
#pragma unroll
    for (int r = 0; r < 8; r++) cs[r][t] = ctx[(size_t)(n0 + r) * Ee + t];
    __syncthreads();
    float acc[8];
    const float bt = bo[t];
#pragma unroll
    for (int r = 0; r < 8; r++) acc[r] = bt;
    for (int e = 0; e < Ee; e++) {
        const float w = wo[(size_t)e * Ee + t];
#pragma unroll
        for (int r = 0; r < 8; r++) acc[r] += cs[r][e] * w;
    }
    const float gt = lng[t], bb = lnb[t];
    const float winv = 1.0f / wsum_p[0];
    const int wid = t >> 6, lane = t & 63;
    float outacc = 0.0f;
    for (int r = 0; r < 8; r++) {
        const float x = acc[r] + fused[(size_t)(n0 + r) * Ee + t];
        float s1 = x, s2 = x * x;
#pragma unroll
        for (int off = 32; off > 0; off >>= 1) {
            s1 += __shfl_down(s1, off, 64);
            s2 += __shfl_down(s2, off, 64);
        }
        if (lane == 0) { red1[wid] = s1; red2[wid] = s2; }
        __syncthreads();
        float ts1 = 0.0f, ts2 = 0.0f;
#pragma unroll
        for (int w2 = 0; w2 < 6; w2++) { ts1 += red1[w2]; ts2 += red2[w2]; }
        __syncthreads();
        const float mu = ts1 * (1.0f / Ee);
        const float var = ts2 * (1.0f / Ee) - mu * mu;
        const float xn = (x - mu) * rsqrtf(var + 1e-5f) * gt + bb;
        outacc += xn * (rw[n0 + r] * winv);
    }
    part[(size_t)blockIdx.x * Ee + t] = outacc;
}

// ---------------- kernel 5: ordered partial reduce + L2 normalize ----------------
__global__ __launch_bounds__(384) void k_final(const float* __restrict__ part,
                                               float* __restrict__ outp) {
    __shared__ float red[6];
    const int t = threadIdx.x;
    float s = 0.0f;
    for (int b = 0; b < Nn / 8; b++) s += part[(size_t)b * Ee + t];
    float q2 = s * s;
#pragma unroll
    for (int off = 32; off > 0; off >>= 1) q2 += __shfl_down(q2, off, 64);
    const int wid = t >> 6, lane = t & 63;
    if (lane == 0) red[wid] = q2;
    __syncthreads();
    float tot = 0.0f;
#pragma unroll
    for (int w = 0; w < 6; w++) tot += red[w];
    outp[t] = s / (sqrtf(tot) + 1e-8f);
}

extern "C" void kernel_launch(void* const* d_in, const int* in_sizes, int n_in,
                              void* d_out, int out_size, void* d_ws, size_t ws_size,
                              hipStream_t stream) {
    const float* low  = (const float*)d_in[0];
    const float* high = (const float*)d_in[1];
    const float* rw   = (const float*)d_in[2];
    const float* lw1  = (const float*)d_in[3];
    const float* lb1  = (const float*)d_in[4];
    const float* lw2  = (const float*)d_in[5];
    const float* lb2  = (const float*)d_in[6];
    const float* hw1  = (const float*)d_in[7];
    const float* hb1  = (const float*)d_in[8];
    const float* hw2  = (const float*)d_in[9];
    const float* hb2  = (const float*)d_in[10];
    const float* lf   = (const float*)d_in[11];
    const float* wqkv = (const float*)d_in[12];
    const float* bqkv = (const float*)d_in[13];
    const float* wo   = (const float*)d_in[14];
    const float* bo   = (const float*)d_in[15];
    const float* lng  = (const float*)d_in[16];
    const float* lnb  = (const float*)d_in[17];

    float* ws    = (float*)d_ws;
    const size_t NE = (size_t)Nn * Ee;
    float* fused = ws;                       // NE f32
    float* ctx   = ws + NE;                  // NE f32
    float* part  = ws + 2 * NE;              // (Nn/8)*Ee f32
    float* wsum  = part + (size_t)(Nn / 8) * Ee;  // 1 f32
    ushort_t* qb = (ushort_t*)(wsum + 4);    // NE bf16 (16B-aligned)
    ushort_t* kb = qb + NE;                  // NE bf16
    ushort_t* vtb = kb + NE;                 // NE bf16 (transposed [H][DH][N])

    hipLaunchKernelGGL(k_wsum, dim3(1), dim3(256), 0, stream, rw, wsum);
    hipLaunchKernelGGL(k_fused, dim3(Nn / 4), dim3(384), 0, stream,
                       low, high, lf, lw1, lb1, lw2, lb2, hw1, hb1, hw2, hb2, fused);
    hipLaunchKernelGGL(k_qkv, dim3(Nn / 8), dim3(384), 0, stream,
                       fused, wqkv, bqkv, qb, kb, vtb);
    hipLaunchKernelGGL(k_attn, dim3(Nn / 32, Hh), dim3(128), 0, stream, qb, kb, vtb, ctx);
    hipLaunchKernelGGL(k_out, dim3(Nn / 8), dim3(384), 0, stream,
                       ctx, fused, wo, bo, lng, lnb, rw, wsum, part);
    hipLaunchKernelGGL(k_final, dim3(1), dim3(384), 0, stream, part, (float*)d_out);
}

// Round 3
// 195.829 us; speedup vs baseline: 4.4109x; 1.8803x over previous
//
#include <hip/hip_runtime.h>
#include <math.h>

#define Nn 4096
#define Ee 384
#define Hh 6
#define DHh 64
#define MIDm 96
#define TEe 1152
#define SPLIT 4

typedef short s16x8 __attribute__((ext_vector_type(8)));
typedef float f32x4 __attribute__((ext_vector_type(4)));
typedef float f32x16 __attribute__((ext_vector_type(16)));
typedef float f32x2 __attribute__((ext_vector_type(2)));
typedef unsigned short ushort_t;
typedef unsigned short ushort4_t __attribute__((ext_vector_type(4)));

#define CROW(r, hf) ((((r) & 3)) + 8 * ((r) >> 2) + 4 * (hf))

__device__ __forceinline__ float gelu_exact(float x) {
    return 0.5f * x * (1.0f + erff(x * 0.70710678118654752f));
}
__device__ __forceinline__ float sigmoidf_(float x) {
    return 1.0f / (1.0f + __expf(-x));
}
__device__ __forceinline__ ushort_t f2bf(float x) {
    unsigned int u = __float_as_uint(x);
    u = (u + 0x7FFFu + ((u >> 16) & 1u)) >> 16;
    return (ushort_t)u;
}
__device__ __forceinline__ float bf2f(ushort_t u) {
    return __uint_as_float(((unsigned int)u) << 16);
}
__device__ __forceinline__ unsigned int cvtpk(float a, float b) {
    unsigned int r;
    asm("v_cvt_pk_bf16_f32 %0, %1, %2" : "=v"(r) : "v"(a), "v"(b));
    return r;
}

// weight-region offsets (ushort units)
#define W1L_OFF 0
#define W1H_OFF 36864
#define W2L_OFF 73728
#define W2H_OFF 110592
#define WQKV_OFF 147456
#define WO_OFF 589824

// ---------------- kernel: convert + transpose weights / activations to bf16 ----------------
__global__ __launch_bounds__(256) void k_cvt(
    const float* __restrict__ low, const float* __restrict__ high,
    const float* __restrict__ lw1, const float* __restrict__ hw1,
    const float* __restrict__ lw2, const float* __restrict__ hw2,
    const float* __restrict__ wqkv, const float* __restrict__ wo,
    ushort_t* __restrict__ lowb, ushort_t* __restrict__ highb,
    ushort_t* __restrict__ wT) {
    const int NE = Nn * Ee;  // 1572864
    const int T1 = NE, T2 = 2 * NE;
    const int W1N = 36864, W2N = 36864, WQN = 442368, WON = 147456;
    const int T3 = T2 + W1N, T4 = T3 + W1N, T5 = T4 + W2N, T6 = T5 + W2N;
    const int T7 = T6 + WQN, T8 = T7 + WON;
    for (int i = blockIdx.x * 256 + threadIdx.x; i < T8; i += gridDim.x * 256) {
        if (i < T1) {
            lowb[i] = f2bf(low[i]);
        } else if (i < T2) {
            highb[i - T1] = f2bf(high[i - T1]);
        } else if (i < T3) {
            int j = i - T2, m = j / 384, k = j % 384;
            wT[W1L_OFF + j] = f2bf(lw1[k * MIDm + m]);
        } else if (i < T4) {
            int j = i - T3, m = j / 384, k = j % 384;
            wT[W1H_OFF + j] = f2bf(hw1[k * MIDm + m]);
        } else if (i < T5) {
            int j = i - T4, e = j / MIDm, m = j % MIDm;
            wT[W2L_OFF + j] = f2bf(lw2[m * Ee + e]);
        } else if (i < T6) {
            int j = i - T5, e = j / MIDm, m = j % MIDm;
            wT[W2H_OFF + j] = f2bf(hw2[m * Ee + e]);
        } else if (i < T7) {
            int j = i - T6, n = j / 384, k = j % 384;
            wT[WQKV_OFF + j] = f2bf(wqkv[k * TEe + n]);
        } else {
            int j = i - T7, n = j / 384, k = j % 384;
            wT[WO_OFF + j] = f2bf(wo[k * Ee + n]);
        }
    }
}

// ---------------- kernel: sum(ref_w) ----------------
__global__ __launch_bounds__(256) void k_wsum(const float* __restrict__ rw,
                                              float* __restrict__ wsum) {
    __shared__ float red[4];
    const int t = threadIdx.x;
    float s = 0.0f;
    for (int i = t; i < Nn; i += 256) s += rw[i];
#pragma unroll
    for (int off = 32; off > 0; off >>= 1) s += __shfl_down(s, off, 64);
    if ((t & 63) == 0) red[t >> 6] = s;
    __syncthreads();
    if (t == 0) {
        float a = 0.0f;
#pragma unroll
        for (int w = 0; w < 4; w++) a += red[w];
        wsum[0] = a;
    }
}

// ---------------- kernel: dual channel-MLP + layer fuse (MFMA) ----------------
// grid 128 x 128 thr (2 waves: wave = stream); 32 rows/block
__global__ __launch_bounds__(128) void k_fused(
    const float* __restrict__ low, const float* __restrict__ high,
    const ushort_t* __restrict__ lowb, const ushort_t* __restrict__ highb,
    const float* __restrict__ lf, const ushort_t* __restrict__ wT,
    const float* __restrict__ lb1, const float* __restrict__ lb2,
    const float* __restrict__ hb1, const float* __restrict__ hb2,
    float* __restrict__ fused, ushort_t* __restrict__ fusedb) {
    __shared__ ushort_t Hs[2][32][104];
    __shared__ float Sg[2][32][196];
    const int t = threadIdx.x;
    const int st = t >> 6, l = t & 63, ll = l & 31, hf = l >> 5;
    const int rb = blockIdx.x * 32;
    const ushort_t* Xb = st ? highb : lowb;
    const ushort_t* w1T = wT + (st ? W1H_OFF : W1L_OFF);
    const ushort_t* w2T = wT + (st ? W2H_OFF : W2L_OFF);
    const float* b1p = st ? hb1 : lb1;
    const float* b2p = st ? hb2 : lb2;
    // GEMM1: H = gelu(X @ W1 + b1)
    f32x16 hA[3];
#pragma unroll
    for (int nt = 0; nt < 3; nt++)
#pragma unroll
        for (int r = 0; r < 16; r++) hA[nt][r] = 0.0f;
    for (int ks = 0; ks < 24; ks++) {
        s16x8 af = *(const s16x8*)&Xb[(rb + ll) * 384 + ks * 16 + hf * 8];
#pragma unroll
        for (int nt = 0; nt < 3; nt++) {
            s16x8 bf = *(const s16x8*)&w1T[(nt * 32 + ll) * 384 + ks * 16 + hf * 8];
            hA[nt] = __builtin_amdgcn_mfma_f32_32x32x16_bf16(af, bf, hA[nt], 0, 0, 0);
        }
    }
#pragma unroll
    for (int nt = 0; nt < 3; nt++) {
        float bb = b1p[nt * 32 + ll];
#pragma unroll
        for (int r = 0; r < 16; r++)
            Hs[st][CROW(r, hf)][nt * 32 + ll] = f2bf(gelu_exact(hA[nt][r] + bb));
    }
    const float a0 = lf[0], a1 = lf[1];
    const float mx = fmaxf(a0, a1);
    const float e0 = __expf(a0 - mx), e1 = __expf(a1 - mx);
    const float inv = 1.0f / (e0 + e1);
    const float w0 = e0 * inv, w1v = e1 * inv;
    // GEMM2 + gate + fuse, in two 192-col halves
    for (int nh = 0; nh < 2; nh++) {
        f32x16 sA[6];
#pragma unroll
        for (int nt = 0; nt < 6; nt++)
#pragma unroll
            for (int r = 0; r < 16; r++) sA[nt][r] = 0.0f;
#pragma unroll
        for (int ks = 0; ks < 6; ks++) {
            s16x8 af = *(const s16x8*)&Hs[st][ll][ks * 16 + hf * 8];
#pragma unroll
            for (int nt = 0; nt < 6; nt++) {
                s16x8 bf = *(const s16x8*)&w2T[(nh * 192 + nt * 32 + ll) * MIDm + ks * 16 + hf * 8];
                sA[nt] = __builtin_amdgcn_mfma_f32_32x32x16_bf16(af, bf, sA[nt], 0, 0, 0);
            }
        }
#pragma unroll
        for (int nt = 0; nt < 6; nt++) {
            float bb = b2p[nh * 192 + nt * 32 + ll];
#pragma unroll
            for (int r = 0; r < 16; r++)
                Sg[st][CROW(r, hf)][nt * 32 + ll] = sigmoidf_(sA[nt][r] + bb);
        }
        __syncthreads();
        for (int idx = t; idx < 32 * 192; idx += 128) {
            int row = idx / 192, c = idx % 192;
            int e = nh * 192 + c, gr = rb + row;
            float f = w0 * low[gr * 384 + e] * Sg[0][row][c] +
                      w1v * high[gr * 384 + e] * Sg[1][row][c];
            fused[gr * 384 + e] = f;
            fusedb[gr * 384 + e] = f2bf(f);
        }
        __syncthreads();
    }
}

// ---------------- kernel: qkv projection (MFMA) ----------------
// grid (128, 2) x 128 thr; q,k row-major [H][N][64] bf16 (q pre-scaled); v transposed [H][64][N]
__global__ __launch_bounds__(128) void k_qkv(
    const ushort_t* __restrict__ fusedb, const ushort_t* __restrict__ wT,
    const float* __restrict__ bqkv,
    ushort_t* __restrict__ qb, ushort_t* __restrict__ kb, ushort_t* __restrict__ vtb) {
    __shared__ float tls[2][32][40];
    const int t = threadIdx.x;
    const int w = t >> 6, l = t & 63, ll = l & 31, hf = l >> 5;
    const int rb = blockIdx.x * 32;
    const int nbase_w = blockIdx.y * 576 + w * 288;
    const ushort_t* wq = wT + WQKV_OFF;
    for (int nt = 0; nt < 9; nt++) {
        const int nb = nbase_w + nt * 32;
        f32x16 acc;
#pragma unroll
        for (int r = 0; r < 16; r++) acc[r] = 0.0f;
        for (int ks = 0; ks < 24; ks++) {
            s16x8 af = *(const s16x8*)&fusedb[(rb + ll) * 384 + ks * 16 + hf * 8];
            s16x8 bf = *(const s16x8*)&wq[(size_t)(nb + ll) * 384 + ks * 16 + hf * 8];
            acc = __builtin_amdgcn_mfma_f32_32x32x16_bf16(af, bf, acc, 0, 0, 0);
        }
        const int which = nb / 384, wn = nb % 384;
        const int hb = wn >> 6, d0 = wn & 63;  // d0 in {0,32}
        const float bias = bqkv[nb + ll];
        if (which == 2) {
            // V: direct transposed store [H][64][N]
            const int d = d0 + ll;
#pragma unroll
            for (int g2 = 0; g2 < 4; g2++) {
                ushort4_t u4;
#pragma unroll
                for (int i2 = 0; i2 < 4; i2++) u4[i2] = f2bf(acc[g2 * 4 + i2] + bias);
                *(ushort4_t*)&vtb[((size_t)(hb * 64 + d)) * Nn + rb + 8 * g2 + 4 * hf] = u4;
            }
        } else {
            const float sc = (which == 0) ? 0.125f : 1.0f;
#pragma unroll
            for (int r = 0; r < 16; r++) tls[w][CROW(r, hf)][ll] = (acc[r] + bias) * sc;
            ushort_t* dst = which ? kb : qb;
            const int row2 = l >> 1, sg = l & 1;
            union { ushort_t us[16]; s16x8 v[2]; } u;
#pragma unroll
            for (int j = 0; j < 16; j++) u.us[j] = f2bf(tls[w][row2][sg * 16 + j]);
            size_t base = ((size_t)hb * Nn + rb + row2) * 64 + d0 + sg * 16;
            *(s16x8*)&dst[base] = u.v[0];
            *(s16x8*)&dst[base + 8] = u.v[1];
        }
    }
}

// ---------------- kernel: flash attention, 32x32x16 MFMA, swapped operands, split-K ----------------
// grid (32, 6, 4) x 256 thr (4 waves x 32 q-rows); KV tile 64; partials f32
__global__ __launch_bounds__(256) void k_attn(
    const ushort_t* __restrict__ qb, const ushort_t* __restrict__ kb,
    const ushort_t* __restrict__ vtb, float* __restrict__ pof,
    float* __restrict__ pml) {
    __shared__ ushort_t Kt[64 * 64];
    __shared__ ushort_t Vt[64 * 64];
    const int t = threadIdx.x;
    const int wid = t >> 6, l = t & 63, ll = l & 31, hf = l >> 5;
    const int h = blockIdx.y, qt = blockIdx.x, sp = blockIdx.z;
    const int qrow0 = qt * 128 + wid * 32;
    // Q as B-fragments (col = q = ll, k = d), resident across all kv tiles
    s16x8 qf[4];
#pragma unroll
    for (int dc = 0; dc < 4; dc++)
        qf[dc] = *(const s16x8*)&qb[((size_t)h * Nn + qrow0 + ll) * 64 + dc * 16 + hf * 8];
    f32x16 o0, o1;
#pragma unroll
    for (int r = 0; r < 16; r++) { o0[r] = 0.0f; o1[r] = 0.0f; }
    float m = -1e30f, lsum = 0.0f;
    for (int kt = 0; kt < Nn / (64 * SPLIT); kt++) {
        const int ktb = (sp * (Nn / (64 * SPLIT)) + kt) * 64;
        __syncthreads();
        for (int j = t; j < 512; j += 256) {
            const int row = j >> 3, colE = (j & 7) * 8;
            const int off = row * 64 + (colE ^ ((row & 7) << 3));
            *(s16x8*)&Kt[off] = *(const s16x8*)&kb[((size_t)h * Nn + ktb + row) * 64 + colE];
            *(s16x8*)&Vt[off] = *(const s16x8*)&vtb[((size_t)h * 64 + row) * Nn + ktb + colE];
        }
        __syncthreads();
        // S^T = K @ Q^T : lane owns q-column ll, kv rows crow(r,hf)+32a
        f32x16 s0, s1;
#pragma unroll
        for (int r = 0; r < 16; r++) { s0[r] = 0.0f; s1[r] = 0.0f; }
#pragma unroll
        for (int dc = 0; dc < 4; dc++) {
            const int colE = dc * 16 + hf * 8;
            s16x8 kf0 = *(const s16x8*)&Kt[ll * 64 + (colE ^ ((ll & 7) << 3))];
            s16x8 kf1 = *(const s16x8*)&Kt[(32 + ll) * 64 + (colE ^ ((ll & 7) << 3))];
            s0 = __builtin_amdgcn_mfma_f32_32x32x16_bf16(kf0, qf[dc], s0, 0, 0, 0);
            s1 = __builtin_amdgcn_mfma_f32_32x32x16_bf16(kf1, qf[dc], s1, 0, 0, 0);
        }
        // online softmax (in-register; one cross-half swap)
        float mloc = s0[0];
#pragma unroll
        for (int r = 1; r < 16; r++) mloc = fmaxf(mloc, s0[r]);
#pragma unroll
        for (int r = 0; r < 16; r++) mloc = fmaxf(mloc, s1[r]);
        mloc = fmaxf(mloc, __shfl_xor(mloc, 32, 64));
        const float mnew = fmaxf(m, mloc);
        const float scl = __expf(m - mnew);
        m = mnew;
        float ls = 0.0f;
#pragma unroll
        for (int r = 0; r < 16; r++) { s0[r] = __expf(s0[r] - mnew); ls += s0[r]; }
#pragma unroll
        for (int r = 0; r < 16; r++) { s1[r] = __expf(s1[r] - mnew); ls += s1[r]; }
        ls += __shfl_xor(ls, 32, 64);
        lsum = lsum * scl + ls;
#pragma unroll
        for (int r = 0; r < 16; r++) { o0[r] *= scl; o1[r] *= scl; }
        // P^T fragments in-register (B operand of PV), then O^T += V^T @ P^T
#pragma unroll
        for (int ks = 0; ks < 4; ks++) {
            const f32x16 S = (ks < 2) ? s0 : s1;
            const int b = (ks & 1) * 8;
            unsigned int t1 = cvtpk(S[b + 0], S[b + 1]);
            unsigned int t3 = cvtpk(S[b + 2], S[b + 3]);
            unsigned int t2 = cvtpk(S[b + 4], S[b + 5]);
            unsigned int t4 = cvtpk(S[b + 6], S[b + 7]);
            unsigned int t1p = __shfl_xor(t1, 32, 64);
            unsigned int t2p = __shfl_xor(t2, 32, 64);
            unsigned int t3p = __shfl_xor(t3, 32, 64);
            unsigned int t4p = __shfl_xor(t4, 32, 64);
            union { unsigned int w[4]; s16x8 v; } u;
            u.w[0] = hf ? t2p : t1;
            u.w[1] = hf ? t4p : t3;
            u.w[2] = hf ? t2 : t1p;
            u.w[3] = hf ? t4 : t3p;
            const int colE = ks * 16 + hf * 8;
            s16x8 vf0 = *(const s16x8*)&Vt[ll * 64 + (colE ^ ((ll & 7) << 3))];
            s16x8 vf1 = *(const s16x8*)&Vt[(32 + ll) * 64 + (colE ^ ((ll & 7) << 3))];
            o0 = __builtin_amdgcn_mfma_f32_32x32x16_bf16(vf0, u.v, o0, 0, 0, 0);
            o1 = __builtin_amdgcn_mfma_f32_32x32x16_bf16(vf1, u.v, o1, 0, 0, 0);
        }
    }
    // write unnormalized partials (coalesced along q) + stats
#pragma unroll
    for (int r = 0; r < 16; r++) {
        const int d_a = CROW(r, hf), d_b = 32 + CROW(r, hf);
        pof[((size_t)(sp * Ee + h * 64 + d_a)) * Nn + qrow0 + ll] = o0[r];
        pof[((size_t)(sp * Ee + h * 64 + d_b)) * Nn + qrow0 + ll] = o1[r];
    }
    if (hf == 0) {
        const size_t ix = 2 * (((size_t)sp * Hh + h) * Nn + qrow0 + ll);
        pml[ix] = m;
        pml[ix + 1] = lsum;
    }
}

// ---------------- kernel: split-K merge -> ctx bf16 [N][E] ----------------
// grid 64 x 256
__global__ __launch_bounds__(256) void k_merge(
    const float* __restrict__ pof, const float* __restrict__ pml,
    ushort_t* __restrict__ ctxb) {
    __shared__ float mls[SPLIT][Hh][64][2];
    __shared__ float wls[SPLIT][Hh][64];
    __shared__ ushort_t tile[64][384];
    const int t = threadIdx.x;
    const int qb0 = blockIdx.x * 64;
    for (int i = t; i < SPLIT * Hh * 64; i += 256) {
        const int s = i / (Hh * 64), r2 = i % (Hh * 64);
        const int hh = r2 / 64, qq = r2 % 64;
        const size_t ix = 2 * (((size_t)s * Hh + hh) * Nn + qb0 + qq);
        mls[s][hh][qq][0] = pml[ix];
        mls[s][hh][qq][1] = pml[ix + 1];
    }
    __syncthreads();
    for (int i = t; i < Hh * 64; i += 256) {
        const int hh = i / 64, qq = i % 64;
        float M = mls[0][hh][qq][0];
#pragma unroll
        for (int s = 1; s < SPLIT; s++) M = fmaxf(M, mls[s][hh][qq][0]);
        float den = 0.0f;
#pragma unroll
        for (int s = 0; s < SPLIT; s++) den += __expf(mls[s][hh][qq][0] - M) * mls[s][hh][qq][1];
        const float dinv = 1.0f / den;
#pragma unroll
        for (int s = 0; s < SPLIT; s++) wls[s][hh][qq] = __expf(mls[s][hh][qq][0] - M) * dinv;
    }
    __syncthreads();
    const int qq = t & 63, e0 = t >> 6;
    for (int i = 0; i < 96; i++) {
        const int e = e0 + 4 * i;
        const int hh = e >> 6;
        float acc = 0.0f;
#pragma unroll
        for (int s = 0; s < SPLIT; s++)
            acc += wls[s][hh][qq] * pof[((size_t)(s * Ee + e)) * Nn + qb0 + qq];
        tile[qq][e] = f2bf(acc);
    }
    __syncthreads();
    for (int i = t; i < 64 * 48; i += 256) {
        const int q2 = i / 48, sg = i % 48;
        *(s16x8*)&ctxb[((size_t)(qb0 + q2)) * 384 + sg * 8] = *(const s16x8*)&tile[q2][sg * 8];
    }
}

// ---------------- kernel: out-projection + residual -> x (f32) ----------------
// grid (128, 2) x 128 thr
__global__ __launch_bounds__(128) void k_oproj(
    const ushort_t* __restrict__ ctxb, const ushort_t* __restrict__ wT,
    const float* __restrict__ bo, const float* __restrict__ fused,
    float* __restrict__ xws) {
    __shared__ float tlso[2][32][40];
    const int t = threadIdx.x;
    const int w = t >> 6, l = t & 63, ll = l & 31, hf = l >> 5;
    const int rb = blockIdx.x * 32;
    const int nbase = blockIdx.y * 192 + w * 96;
    const ushort_t* woT = wT + WO_OFF;
    for (int nt = 0; nt < 3; nt++) {
        const int nb = nbase + nt * 32;
        f32x16 acc;
#pragma unroll
        for (int r = 0; r < 16; r++) acc[r] = 0.0f;
        for (int ks = 0; ks < 24; ks++) {
            s16x8 af = *(const s16x8*)&ctxb[(rb + ll) * 384 + ks * 16 + hf * 8];
            s16x8 bf = *(const s16x8*)&woT[(size_t)(nb + ll) * 384 + ks * 16 + hf * 8];
            acc = __builtin_amdgcn_mfma_f32_32x32x16_bf16(af, bf, acc, 0, 0, 0);
        }
        const float bias = bo[nb + ll];
#pragma unroll
        for (int r = 0; r < 16; r++) tlso[w][CROW(r, hf)][ll] = acc[r] + bias;
        const int row2 = l >> 1, sg = l & 1;
#pragma unroll
        for (int j4 = 0; j4 < 4; j4++) {
            f32x4 v = *(const f32x4*)&tlso[w][row2][sg * 16 + j4 * 4];
            f32x4 fu = *(const f32x4*)&fused[(size_t)(rb + row2) * 384 + nb + sg * 16 + j4 * 4];
            v += fu;
            *(f32x4*)&xws[(size_t)(rb + row2) * 384 + nb + sg * 16 + j4 * 4] = v;
        }
    }
}

// ---------------- kernel: LayerNorm + weighted partials ----------------
__global__ __launch_bounds__(384) void k_ln(
    const float* __restrict__ xws, const float* __restrict__ lng,
    const float* __restrict__ lnb, const float* __restrict__ rw,
    const float* __restrict__ wsum_p, float* __restrict__ part) {
    __shared__ float red1[6], red2[6];
    const int t = threadIdx.x;
    const int n0 = blockIdx.x * 8;
    const float gt = lng[t], bb = lnb[t];
    const float winv = 1.0f / wsum_p[0];
    const int wid = t >> 6, lane = t & 63;
    float outacc = 0.0f;
    for (int r = 0; r < 8; r++) {
        const float x = xws[(size_t)(n0 + r) * 384 + t];
        float s1 = x, s2 = x * x;
#pragma unroll
        for (int off = 32; off > 0; off >>= 1) {
            s1 += __shfl_down(s1, off, 64);
            s2 += __shfl_down(s2, off, 64);
        }
        if (lane == 0) { red1[wid] = s1; red2[wid] = s2; }
        __syncthreads();
        float ts1 = 0.0f, ts2 = 0.0f;
#pragma unroll
        for (int w2 = 0; w2 < 6; w2++) { ts1 += red1[w2]; ts2 += red2[w2]; }
        __syncthreads();
        const float mu = ts1 * (1.0f / Ee);
        const float var = ts2 * (1.0f / Ee) - mu * mu;
        const float xn = (x - mu) * rsqrtf(var + 1e-5f) * gt + bb;
        outacc += xn * (rw[n0 + r] * winv);
    }
    part[(size_t)blockIdx.x * Ee + t] = outacc;
}

// ---------------- kernel: ordered partial reduce + L2 normalize ----------------
__global__ __launch_bounds__(384) void k_final(const float* __restrict__ part,
                                               float* __restrict__ outp) {
    __shared__ float red[6];
    const int t = threadIdx.x;
    float s = 0.0f;
    for (int b = 0; b < Nn / 8; b++) s += part[(size_t)b * Ee + t];
    float q2 = s * s;
#pragma unroll
    for (int off = 32; off > 0; off >>= 1) q2 += __shfl_down(q2, off, 64);
    const int wid = t >> 6, lane = t & 63;
    if (lane == 0) red[wid] = q2;
    __syncthreads();
    float tot = 0.0f;
#pragma unroll
    for (int w = 0; w < 6; w++) tot += red[w];
    outp[t] = s / (sqrtf(tot) + 1e-8f);
}

extern "C" void kernel_launch(void* const* d_in, const int* in_sizes, int n_in,
                              void* d_out, int out_size, void* d_ws, size_t ws_size,
                              hipStream_t stream) {
    const float* low  = (const float*)d_in[0];
    const float* high = (const float*)d_in[1];
    const float* rw   = (const float*)d_in[2];
    const float* lw1  = (const float*)d_in[3];
    const float* lb1  = (const float*)d_in[4];
    const float* lw2  = (const float*)d_in[5];
    const float* lb2  = (const float*)d_in[6];
    const float* hw1  = (const float*)d_in[7];
    const float* hb1  = (const float*)d_in[8];
    const float* hw2  = (const float*)d_in[9];
    const float* hb2  = (const float*)d_in[10];
    const float* lf   = (const float*)d_in[11];
    const float* wqkv = (const float*)d_in[12];
    const float* bqkv = (const float*)d_in[13];
    const float* wo   = (const float*)d_in[14];
    const float* bo   = (const float*)d_in[15];
    const float* lng  = (const float*)d_in[16];
    const float* lnb  = (const float*)d_in[17];

    float* ws = (float*)d_ws;
    // f32 region
    float* fused = ws;                        // 1,572,864
    float* part  = ws + 1572864;              // 196,608
    float* wsum  = ws + 1769472;              // 16
    float* pml   = ws + 1769488;              // 196,608
    float* pof   = ws + 1966096;              // 6,291,456 (x aliases after merge)
    float* xws   = pof;
    // bf16 region
    ushort_t* u16base = (ushort_t*)(ws + 8257552);
    ushort_t* lowb   = u16base;               // qb aliases after k_fused
    ushort_t* highb  = u16base + 1572864;     // kb aliases
    ushort_t* fusedb = u16base + 3145728;     // ctxb aliases after k_qkv
    ushort_t* vtb    = u16base + 4718592;
    ushort_t* wT     = u16base + 6291456;     // 737,280
    ushort_t* qb = lowb;
    ushort_t* kb = highb;
    ushort_t* ctxb = fusedb;

    hipLaunchKernelGGL(k_cvt, dim3(1024), dim3(256), 0, stream,
                       low, high, lw1, hw1, lw2, hw2, wqkv, wo, lowb, highb, wT);
    hipLaunchKernelGGL(k_wsum, dim3(1), dim3(256), 0, stream, rw, wsum);
    hipLaunchKernelGGL(k_fused, dim3(128), dim3(128), 0, stream,
                       low, high, lowb, highb, lf, wT, lb1, lb2, hb1, hb2, fused, fusedb);
    hipLaunchKernelGGL(k_qkv, dim3(128, 2), dim3(128), 0, stream,
                       fusedb, wT, bqkv, qb, kb, vtb);
    hipLaunchKernelGGL(k_attn, dim3(32, Hh, SPLIT), dim3(256), 0, stream,
                       qb, kb, vtb, pof, pml);
    hipLaunchKernelGGL(k_merge, dim3(64), dim3(256), 0, stream, pof, pml, ctxb);
    hipLaunchKernelGGL(k_oproj, dim3(128, 2), dim3(128), 0, stream,
                       ctxb, wT, bo, fused, xws);
    hipLaunchKernelGGL(k_ln, dim3(512), dim3(384), 0, stream,
                       xws, lng, lnb, rw, wsum, part);
    hipLaunchKernelGGL(k_final, dim3(1), dim3(384), 0, stream, part, (float*)d_out);
}

// Round 4
// 187.253 us; speedup vs baseline: 4.6129x; 1.0458x over previous
//
#include <hip/hip_runtime.h>
#include <math.h>

#define Nn 4096
#define Ee 384
#define Hh 6
#define DHh 64
#define MIDm 96
#define TEe 1152
#define SPLIT 8

typedef short s16x8 __attribute__((ext_vector_type(8)));
typedef float f32x4 __attribute__((ext_vector_type(4)));
typedef float f32x16 __attribute__((ext_vector_type(16)));
typedef unsigned short ushort_t;
typedef unsigned short ushort4_t __attribute__((ext_vector_type(4)));

#define CROW(r, hf) ((((r) & 3)) + 8 * ((r) >> 2) + 4 * (hf))

__device__ __forceinline__ float gelu_exact(float x) {
    return 0.5f * x * (1.0f + erff(x * 0.70710678118654752f));
}
__device__ __forceinline__ float sigmoidf_(float x) {
    return 1.0f / (1.0f + __expf(-x));
}
__device__ __forceinline__ ushort_t f2bf(float x) {
    unsigned int u = __float_as_uint(x);
    u = (u + 0x7FFFu + ((u >> 16) & 1u)) >> 16;
    return (ushort_t)u;
}
__device__ __forceinline__ float bf2f(ushort_t u) {
    return __uint_as_float(((unsigned int)u) << 16);
}
__device__ __forceinline__ unsigned int cvtpk(float a, float b) {
    unsigned int r;
    asm("v_cvt_pk_bf16_f32 %0, %1, %2" : "=v"(r) : "v"(a), "v"(b));
    return r;
}

// weight-region offsets (ushort units)
#define W1L_OFF 0
#define W1H_OFF 36864
#define W2L_OFF 73728
#define W2H_OFF 110592
#define WQKV_OFF 147456
#define WO_OFF 589824

// ---------------- kernel: convert + transpose weights / activations to bf16 ----------------
__global__ __launch_bounds__(256) void k_cvt(
    const float* __restrict__ low, const float* __restrict__ high,
    const float* __restrict__ lw1, const float* __restrict__ hw1,
    const float* __restrict__ lw2, const float* __restrict__ hw2,
    const float* __restrict__ wqkv, const float* __restrict__ wo,
    ushort_t* __restrict__ lowb, ushort_t* __restrict__ highb,
    ushort_t* __restrict__ wT) {
    const int NE = Nn * Ee;
    const int T1 = NE, T2 = 2 * NE;
    const int W1N = 36864, W2N = 36864, WQN = 442368, WON = 147456;
    const int T3 = T2 + W1N, T4 = T3 + W1N, T5 = T4 + W2N, T6 = T5 + W2N;
    const int T7 = T6 + WQN, T8 = T7 + WON;
    for (int i = blockIdx.x * 256 + threadIdx.x; i < T8; i += gridDim.x * 256) {
        if (i < T1) {
            lowb[i] = f2bf(low[i]);
        } else if (i < T2) {
            highb[i - T1] = f2bf(high[i - T1]);
        } else if (i < T3) {
            int j = i - T2, m = j / 384, k = j % 384;
            wT[W1L_OFF + j] = f2bf(lw1[k * MIDm + m]);
        } else if (i < T4) {
            int j = i - T3, m = j / 384, k = j % 384;
            wT[W1H_OFF + j] = f2bf(hw1[k * MIDm + m]);
        } else if (i < T5) {
            int j = i - T4, e = j / MIDm, m = j % MIDm;
            wT[W2L_OFF + j] = f2bf(lw2[m * Ee + e]);
        } else if (i < T6) {
            int j = i - T5, e = j / MIDm, m = j % MIDm;
            wT[W2H_OFF + j] = f2bf(hw2[m * Ee + e]);
        } else if (i < T7) {
            int j = i - T6, n = j / 384, k = j % 384;
            wT[WQKV_OFF + j] = f2bf(wqkv[k * TEe + n]);
        } else {
            int j = i - T7, n = j / 384, k = j % 384;
            wT[WO_OFF + j] = f2bf(wo[k * Ee + n]);
        }
    }
}

// ---------------- kernel: sum(ref_w) ----------------
__global__ __launch_bounds__(256) void k_wsum(const float* __restrict__ rw,
                                              float* __restrict__ wsum) {
    __shared__ float red[4];
    const int t = threadIdx.x;
    float s = 0.0f;
    for (int i = t; i < Nn; i += 256) s += rw[i];
#pragma unroll
    for (int off = 32; off > 0; off >>= 1) s += __shfl_down(s, off, 64);
    if ((t & 63) == 0) red[t >> 6] = s;
    __syncthreads();
    if (t == 0) {
        float a = 0.0f;
#pragma unroll
        for (int w = 0; w < 4; w++) a += red[w];
        wsum[0] = a;
    }
}

// ---------------- kernel: MLPs + fuse + QKV, all in one (MFMA) ----------------
// grid 128 x 256 thr (4 waves); 32 rows/block
// q pre-scaled by 0.125*log2(e) for exp2-domain softmax
__global__ __launch_bounds__(256) void k_pre(
    const float* __restrict__ low, const float* __restrict__ high,
    const ushort_t* __restrict__ lowb, const ushort_t* __restrict__ highb,
    const float* __restrict__ lf, const ushort_t* __restrict__ wT,
    const float* __restrict__ lb1, const float* __restrict__ lb2,
    const float* __restrict__ hb1, const float* __restrict__ hb2,
    const float* __restrict__ bqkv,
    float* __restrict__ fused, ushort_t* __restrict__ fusedb,
    ushort_t* __restrict__ qb, ushort_t* __restrict__ kb,
    ushort_t* __restrict__ vtb) {
    __shared__ ushort_t Hs[2][32][104];
    __shared__ ushort_t Sg[2][32][384];
    __shared__ float tls[4][32][40];
    const int t = threadIdx.x;
    const int w = t >> 6, l = t & 63, ll = l & 31, hf = l >> 5;
    const int st = w >> 1, sub = w & 1;
    const int rb = blockIdx.x * 32;
    const ushort_t* Xb = st ? highb : lowb;
    const ushort_t* w1T = wT + (st ? W1H_OFF : W1L_OFF);
    const ushort_t* w2T = wT + (st ? W2H_OFF : W2L_OFF);
    const float* b1p = st ? hb1 : lb1;
    const float* b2p = st ? hb2 : lb2;
    // ---- GEMM1: H = gelu(X @ W1 + b1); wave (st,sub): sub0 -> nt{0,1}, sub1 -> nt{2}
    {
        const int ntn = sub ? 1 : 2;
        const int nt0 = sub ? 2 : 0;
        f32x16 hA[2];
#pragma unroll
        for (int nt = 0; nt < 2; nt++)
#pragma unroll
            for (int r = 0; r < 16; r++) hA[nt][r] = 0.0f;
        for (int ks = 0; ks < 24; ks++) {
            s16x8 af = *(const s16x8*)&Xb[(rb + ll) * 384 + ks * 16 + hf * 8];
            for (int nt = 0; nt < ntn; nt++) {
                s16x8 bf = *(const s16x8*)&w1T[((nt0 + nt) * 32 + ll) * 384 + ks * 16 + hf * 8];
                hA[nt] = __builtin_amdgcn_mfma_f32_32x32x16_bf16(af, bf, hA[nt], 0, 0, 0);
            }
        }
        for (int nt = 0; nt < ntn; nt++) {
            float bb = b1p[(nt0 + nt) * 32 + ll];
#pragma unroll
            for (int r = 0; r < 16; r++)
                Hs[st][CROW(r, hf)][(nt0 + nt) * 32 + ll] = f2bf(gelu_exact(hA[nt][r] + bb));
        }
    }
    __syncthreads();
    // ---- GEMM2: Sg = sigmoid(H @ W2 + b2); wave (st, nh=sub) handles 192-col half
    {
        const int nh = sub;
        f32x16 sA[6];
#pragma unroll
        for (int nt = 0; nt < 6; nt++)
#pragma unroll
            for (int r = 0; r < 16; r++) sA[nt][r] = 0.0f;
#pragma unroll
        for (int ks = 0; ks < 6; ks++) {
            s16x8 af = *(const s16x8*)&Hs[st][ll][ks * 16 + hf * 8];
#pragma unroll
            for (int nt = 0; nt < 6; nt++) {
                s16x8 bf = *(const s16x8*)&w2T[(nh * 192 + nt * 32 + ll) * MIDm + ks * 16 + hf * 8];
                sA[nt] = __builtin_amdgcn_mfma_f32_32x32x16_bf16(af, bf, sA[nt], 0, 0, 0);
            }
        }
#pragma unroll
        for (int nt = 0; nt < 6; nt++) {
            float bb = b2p[nh * 192 + nt * 32 + ll];
#pragma unroll
            for (int r = 0; r < 16; r++)
                Sg[st][CROW(r, hf)][nh * 192 + nt * 32 + ll] = f2bf(sigmoidf_(sA[nt][r] + bb));
        }
    }
    __syncthreads();
    // ---- fuse epilogue (vectorized x4)
    {
        const float a0 = lf[0], a1 = lf[1];
        const float mx = fmaxf(a0, a1);
        const float e0 = __expf(a0 - mx), e1 = __expf(a1 - mx);
        const float inv = 1.0f / (e0 + e1);
        const float w0 = e0 * inv, w1v = e1 * inv;
        for (int base = t * 4; base < 32 * 384; base += 256 * 4) {
            const int row = base / 384, e0i = base % 384;
            const int gr = rb + row;
            f32x4 lo4 = *(const f32x4*)&low[(size_t)gr * 384 + e0i];
            f32x4 hi4 = *(const f32x4*)&high[(size_t)gr * 384 + e0i];
            ushort4_t s0 = *(const ushort4_t*)&Sg[0][row][e0i];
            ushort4_t s1 = *(const ushort4_t*)&Sg[1][row][e0i];
            f32x4 f;
            ushort4_t fb;
#pragma unroll
            for (int i = 0; i < 4; i++) {
                f[i] = w0 * lo4[i] * bf2f(s0[i]) + w1v * hi4[i] * bf2f(s1[i]);
                fb[i] = f2bf(f[i]);
            }
            *(f32x4*)&fused[(size_t)gr * 384 + e0i] = f;
            *(ushort4_t*)&fusedb[(size_t)gr * 384 + e0i] = fb;
        }
    }
    __syncthreads();
    // ---- QKV: wave w covers n-range [w*288, w*288+288)
    const ushort_t* wq = wT + WQKV_OFF;
    for (int nt = 0; nt < 9; nt++) {
        const int nb = w * 288 + nt * 32;
        f32x16 acc;
#pragma unroll
        for (int r = 0; r < 16; r++) acc[r] = 0.0f;
        for (int ks = 0; ks < 24; ks++) {
            s16x8 af = *(const s16x8*)&fusedb[(size_t)(rb + ll) * 384 + ks * 16 + hf * 8];
            s16x8 bf = *(const s16x8*)&wq[(size_t)(nb + ll) * 384 + ks * 16 + hf * 8];
            acc = __builtin_amdgcn_mfma_f32_32x32x16_bf16(af, bf, acc, 0, 0, 0);
        }
        const int which = nb / 384, wn = nb % 384;
        const int hb = wn >> 6, d0 = wn & 63;
        const float bias = bqkv[nb + ll];
        if (which == 2) {
            const int d = d0 + ll;
#pragma unroll
            for (int g2 = 0; g2 < 4; g2++) {
                ushort4_t u4;
#pragma unroll
                for (int i2 = 0; i2 < 4; i2++) u4[i2] = f2bf(acc[g2 * 4 + i2] + bias);
                *(ushort4_t*)&vtb[((size_t)(hb * 64 + d)) * Nn + rb + 8 * g2 + 4 * hf] = u4;
            }
        } else {
            const float sc = (which == 0) ? 0.18033688f : 1.0f;  // 0.125*log2(e) for q
#pragma unroll
            for (int r = 0; r < 16; r++) tls[w][CROW(r, hf)][ll] = (acc[r] + bias) * sc;
            ushort_t* dst = which ? kb : qb;
            const int row2 = l >> 1, sg = l & 1;
            union { ushort_t us[16]; s16x8 v[2]; } u;
#pragma unroll
            for (int j = 0; j < 16; j++) u.us[j] = f2bf(tls[w][row2][sg * 16 + j]);
            size_t base = ((size_t)hb * Nn + rb + row2) * 64 + d0 + sg * 16;
            *(s16x8*)&dst[base] = u.v[0];
            *(s16x8*)&dst[base + 8] = u.v[1];
        }
    }
}

// ---------------- kernel: flash attention, 32x32x16 MFMA, exp2-domain, split-K ----------------
// grid (32, 6, SPLIT) x 256 thr (4 waves x 32 q-rows); KV tile 64; bf16 partials
__global__ __launch_bounds__(256) void k_attn(
    const ushort_t* __restrict__ qb, const ushort_t* __restrict__ kb,
    const ushort_t* __restrict__ vtb, ushort_t* __restrict__ pof,
    float* __restrict__ pml) {
    __shared__ ushort_t Kt[64 * 64];
    __shared__ ushort_t Vt[64 * 64];
    const int t = threadIdx.x;
    const int wid = t >> 6, l = t & 63, ll = l & 31, hf = l >> 5;
    const int h = blockIdx.y, qt = blockIdx.x, sp = blockIdx.z;
    const int qrow0 = qt * 128 + wid * 32;
    s16x8 qf[4];
#pragma unroll
    for (int dc = 0; dc < 4; dc++)
        qf[dc] = *(const s16x8*)&qb[((size_t)h * Nn + qrow0 + ll) * 64 + dc * 16 + hf * 8];
    f32x16 o0, o1;
#pragma unroll
    for (int r = 0; r < 16; r++) { o0[r] = 0.0f; o1[r] = 0.0f; }
    float m = -1e30f, lsum = 0.0f;
    for (int kt = 0; kt < Nn / (64 * SPLIT); kt++) {
        const int ktb = (sp * (Nn / (64 * SPLIT)) + kt) * 64;
        __syncthreads();
        for (int j = t; j < 512; j += 256) {
            const int row = j >> 3, colE = (j & 7) * 8;
            const int off = row * 64 + (colE ^ ((row & 7) << 3));
            *(s16x8*)&Kt[off] = *(const s16x8*)&kb[((size_t)h * Nn + ktb + row) * 64 + colE];
            *(s16x8*)&Vt[off] = *(const s16x8*)&vtb[((size_t)h * 64 + row) * Nn + ktb + colE];
        }
        __syncthreads();
        f32x16 s0, s1;
#pragma unroll
        for (int r = 0; r < 16; r++) { s0[r] = 0.0f; s1[r] = 0.0f; }
#pragma unroll
        for (int dc = 0; dc < 4; dc++) {
            const int colE = dc * 16 + hf * 8;
            s16x8 kf0 = *(const s16x8*)&Kt[ll * 64 + (colE ^ ((ll & 7) << 3))];
            s16x8 kf1 = *(const s16x8*)&Kt[(32 + ll) * 64 + (colE ^ ((ll & 7) << 3))];
            s0 = __builtin_amdgcn_mfma_f32_32x32x16_bf16(kf0, qf[dc], s0, 0, 0, 0);
            s1 = __builtin_amdgcn_mfma_f32_32x32x16_bf16(kf1, qf[dc], s1, 0, 0, 0);
        }
        // online softmax in exp2 domain; defer-max (skip rescale if max grew < 11.5)
        float mloc = s0[0];
#pragma unroll
        for (int r = 1; r < 16; r++) mloc = fmaxf(mloc, s0[r]);
#pragma unroll
        for (int r = 0; r < 16; r++) mloc = fmaxf(mloc, s1[r]);
        mloc = fmaxf(mloc, __shfl_xor(mloc, 32, 64));
        if (!__all(mloc <= m + 11.5f)) {
            const float mnew = fmaxf(m, mloc);
            const float scl = exp2f(m - mnew);
            m = mnew;
            lsum *= scl;
#pragma unroll
            for (int r = 0; r < 16; r++) { o0[r] *= scl; o1[r] *= scl; }
        }
        float ls = 0.0f;
#pragma unroll
        for (int r = 0; r < 16; r++) { s0[r] = exp2f(s0[r] - m); ls += s0[r]; }
#pragma unroll
        for (int r = 0; r < 16; r++) { s1[r] = exp2f(s1[r] - m); ls += s1[r]; }
        ls += __shfl_xor(ls, 32, 64);
        lsum += ls;
#pragma unroll
        for (int ks = 0; ks < 4; ks++) {
            const f32x16 S = (ks < 2) ? s0 : s1;
            const int b = (ks & 1) * 8;
            unsigned int t1 = cvtpk(S[b + 0], S[b + 1]);
            unsigned int t3 = cvtpk(S[b + 2], S[b + 3]);
            unsigned int t2 = cvtpk(S[b + 4], S[b + 5]);
            unsigned int t4 = cvtpk(S[b + 6], S[b + 7]);
            unsigned int t1p = __shfl_xor(t1, 32, 64);
            unsigned int t2p = __shfl_xor(t2, 32, 64);
            unsigned int t3p = __shfl_xor(t3, 32, 64);
            unsigned int t4p = __shfl_xor(t4, 32, 64);
            union { unsigned int w[4]; s16x8 v; } u;
            u.w[0] = hf ? t2p : t1;
            u.w[1] = hf ? t4p : t3;
            u.w[2] = hf ? t2 : t1p;
            u.w[3] = hf ? t4 : t3p;
            const int colE = ks * 16 + hf * 8;
            s16x8 vf0 = *(const s16x8*)&Vt[ll * 64 + (colE ^ ((ll & 7) << 3))];
            s16x8 vf1 = *(const s16x8*)&Vt[(32 + ll) * 64 + (colE ^ ((ll & 7) << 3))];
            o0 = __builtin_amdgcn_mfma_f32_32x32x16_bf16(vf0, u.v, o0, 0, 0, 0);
            o1 = __builtin_amdgcn_mfma_f32_32x32x16_bf16(vf1, u.v, o1, 0, 0, 0);
        }
    }
#pragma unroll
    for (int r = 0; r < 16; r++) {
        const int d_a = CROW(r, hf), d_b = 32 + CROW(r, hf);
        pof[((size_t)(sp * Ee + h * 64 + d_a)) * Nn + qrow0 + ll] = f2bf(o0[r]);
        pof[((size_t)(sp * Ee + h * 64 + d_b)) * Nn + qrow0 + ll] = f2bf(o1[r]);
    }
    if (hf == 0) {
        const size_t ix = 2 * (((size_t)sp * Hh + h) * Nn + qrow0 + ll);
        pml[ix] = m;
        pml[ix + 1] = lsum;
    }
}

// ---------------- kernel: split-K merge -> ctx bf16 [N][E] ----------------
// grid (64, 4) x 256; block = 64 q-rows x 96-col quarter
__global__ __launch_bounds__(256) void k_merge(
    const ushort_t* __restrict__ pof, const float* __restrict__ pml,
    ushort_t* __restrict__ ctxb) {
    __shared__ float mls[SPLIT][Hh][64][2];
    __shared__ float wls[SPLIT][Hh][64];
    __shared__ ushort_t tile[64][96];
    const int t = threadIdx.x;
    const int qb0 = blockIdx.x * 64;
    const int eq = blockIdx.y;
    for (int i = t; i < SPLIT * Hh * 64; i += 256) {
        const int s = i / (Hh * 64), r2 = i % (Hh * 64);
        const int hh = r2 / 64, qq = r2 % 64;
        const size_t ix = 2 * (((size_t)s * Hh + hh) * Nn + qb0 + qq);
        mls[s][hh][qq][0] = pml[ix];
        mls[s][hh][qq][1] = pml[ix + 1];
    }
    __syncthreads();
    for (int i = t; i < Hh * 64; i += 256) {
        const int hh = i / 64, qq = i % 64;
        float M = mls[0][hh][qq][0];
#pragma unroll
        for (int s = 1; s < SPLIT; s++) M = fmaxf(M, mls[s][hh][qq][0]);
        float den = 0.0f;
#pragma unroll
        for (int s = 0; s < SPLIT; s++) den += exp2f(mls[s][hh][qq][0] - M) * mls[s][hh][qq][1];
        const float dinv = 1.0f / den;
#pragma unroll
        for (int s = 0; s < SPLIT; s++) wls[s][hh][qq] = exp2f(mls[s][hh][qq][0] - M) * dinv;
    }
    __syncthreads();
    const int qq = t & 63, e0 = t >> 6;
    for (int i = 0; i < 24; i++) {
        const int el = e0 + 4 * i;
        const int e = eq * 96 + el;
        const int hh = e >> 6;
        float acc = 0.0f;
#pragma unroll
        for (int s = 0; s < SPLIT; s++)
            acc += wls[s][hh][qq] * bf2f(pof[((size_t)(s * Ee + e)) * Nn + qb0 + qq]);
        tile[qq][el] = f2bf(acc);
    }
    __syncthreads();
    for (int i = t; i < 64 * 12; i += 256) {
        const int q2 = i / 12, sg = i % 12;
        *(s16x8*)&ctxb[((size_t)(qb0 + q2)) * 384 + eq * 96 + sg * 8] =
            *(const s16x8*)&tile[q2][sg * 8];
    }
}

// ---------------- kernel: out-proj + residual + LayerNorm + weighted partials ----------------
// grid 128 x 384 thr (6 waves); 32 rows/block, full 384 cols
__global__ __launch_bounds__(384) void k_oln(
    const ushort_t* __restrict__ ctxb, const ushort_t* __restrict__ wT,
    const float* __restrict__ bo, const float* __restrict__ fused,
    const float* __restrict__ lng, const float* __restrict__ lnb,
    const float* __restrict__ rw, const float* __restrict__ wsum_p,
    float* __restrict__ part) {
    __shared__ float xs[32][384];
    __shared__ float stats[32][2];
    const int t = threadIdx.x;
    const int w = t >> 6, l = t & 63, ll = l & 31, hf = l >> 5;
    const int rb = blockIdx.x * 32;
    const ushort_t* woT = wT + WO_OFF;
#pragma unroll
    for (int nt = 0; nt < 2; nt++) {
        const int nb = w * 64 + nt * 32;
        f32x16 acc;
#pragma unroll
        for (int r = 0; r < 16; r++) acc[r] = 0.0f;
        for (int ks = 0; ks < 24; ks++) {
            s16x8 af = *(const s16x8*)&ctxb[(size_t)(rb + ll) * 384 + ks * 16 + hf * 8];
            s16x8 bf = *(const s16x8*)&woT[(size_t)(nb + ll) * 384 + ks * 16 + hf * 8];
            acc = __builtin_amdgcn_mfma_f32_32x32x16_bf16(af, bf, acc, 0, 0, 0);
        }
        const float bias = bo[nb + ll];
#pragma unroll
        for (int r = 0; r < 16; r++) {
            const int mr = CROW(r, hf);
            xs[mr][nb + ll] = acc[r] + bias + fused[(size_t)(rb + mr) * 384 + nb + ll];
        }
    }
    __syncthreads();
    // LN stats: 8 threads per row (t < 256)
    if (t < 256) {
        const int row = t >> 3, j = t & 7;
        float s1 = 0.0f, s2 = 0.0f;
        for (int i = 0; i < 48; i++) {
            const float x = xs[row][j * 48 + i];
            s1 += x;
            s2 += x * x;
        }
#pragma unroll
        for (int off = 1; off < 8; off <<= 1) {
            s1 += __shfl_xor(s1, off, 64);
            s2 += __shfl_xor(s2, off, 64);
        }
        if (j == 0) {
            const float mu = s1 * (1.0f / Ee);
            const float var = s2 * (1.0f / Ee) - mu * mu;
            stats[row][0] = mu;
            stats[row][1] = rsqrtf(var + 1e-5f);
        }
    }
    __syncthreads();
    const float gt = lng[t], bb = lnb[t];
    const float winv = 1.0f / wsum_p[0];
    float outacc = 0.0f;
    for (int r = 0; r < 32; r++) {
        const float xn = (xs[r][t] - stats[r][0]) * stats[r][1] * gt + bb;
        outacc += xn * (rw[rb + r] * winv);
    }
    part[(size_t)blockIdx.x * Ee + t] = outacc;
}

// ---------------- kernel: ordered partial reduce + L2 normalize ----------------
__global__ __launch_bounds__(384) void k_final(const float* __restrict__ part,
                                               float* __restrict__ outp) {
    __shared__ float red[6];
    const int t = threadIdx.x;
    float s = 0.0f;
    for (int b = 0; b < 128; b++) s += part[(size_t)b * Ee + t];
    float q2 = s * s;
#pragma unroll
    for (int off = 32; off > 0; off >>= 1) q2 += __shfl_down(q2, off, 64);
    const int wid = t >> 6, lane = t & 63;
    if (lane == 0) red[wid] = q2;
    __syncthreads();
    float tot = 0.0f;
#pragma unroll
    for (int w = 0; w < 6; w++) tot += red[w];
    outp[t] = s / (sqrtf(tot) + 1e-8f);
}

extern "C" void kernel_launch(void* const* d_in, const int* in_sizes, int n_in,
                              void* d_out, int out_size, void* d_ws, size_t ws_size,
                              hipStream_t stream) {
    const float* low  = (const float*)d_in[0];
    const float* high = (const float*)d_in[1];
    const float* rw   = (const float*)d_in[2];
    const float* lw1  = (const float*)d_in[3];
    const float* lb1  = (const float*)d_in[4];
    const float* lw2  = (const float*)d_in[5];
    const float* lb2  = (const float*)d_in[6];
    const float* hw1  = (const float*)d_in[7];
    const float* hb1  = (const float*)d_in[8];
    const float* hw2  = (const float*)d_in[9];
    const float* hb2  = (const float*)d_in[10];
    const float* lf   = (const float*)d_in[11];
    const float* wqkv = (const float*)d_in[12];
    const float* bqkv = (const float*)d_in[13];
    const float* wo   = (const float*)d_in[14];
    const float* bo   = (const float*)d_in[15];
    const float* lng  = (const float*)d_in[16];
    const float* lnb  = (const float*)d_in[17];

    float* ws = (float*)d_ws;
    const size_t NE = (size_t)Nn * Ee;
    // f32 region
    float* fused = ws;                               // NE
    float* pml   = ws + NE;                          // 2*SPLIT*Hh*Nn = 393216
    float* part  = ws + NE + 393216;                 // 128*384 = 49152
    float* wsum  = ws + NE + 393216 + 49152;         // 16
    // bf16 region
    ushort_t* u16base = (ushort_t*)(ws + NE + 393216 + 49152 + 16);
    ushort_t* lowb   = u16base;                      // NE (qb aliases after k_pre GEMM1? no: lowb used only in k_pre GEMM1; qb separate)
    ushort_t* highb  = u16base + NE;
    ushort_t* fusedb = u16base + 2 * NE;
    ushort_t* vtb    = u16base + 3 * NE;
    ushort_t* qb     = u16base + 4 * NE;
    ushort_t* kb     = u16base + 5 * NE;
    ushort_t* wT     = u16base + 6 * NE;             // 737280
    ushort_t* pof    = wT + 737280;                  // SPLIT*Ee*Nn = 12582912
    ushort_t* ctxb   = fusedb;  // reuse after k_attn is done with... ctxb written by k_merge, fusedb last read in k_pre -> safe

    hipLaunchKernelGGL(k_cvt, dim3(1024), dim3(256), 0, stream,
                       low, high, lw1, hw1, lw2, hw2, wqkv, wo, lowb, highb, wT);
    hipLaunchKernelGGL(k_wsum, dim3(1), dim3(256), 0, stream, rw, wsum);
    hipLaunchKernelGGL(k_pre, dim3(128), dim3(256), 0, stream,
                       low, high, lowb, highb, lf, wT, lb1, lb2, hb1, hb2, bqkv,
                       fused, fusedb, qb, kb, vtb);
    hipLaunchKernelGGL(k_attn, dim3(32, Hh, SPLIT), dim3(256), 0, stream,
                       qb, kb, vtb, pof, pml);
    hipLaunchKernelGGL(k_merge, dim3(64, 4), dim3(256), 0, stream, pof, pml, ctxb);
    hipLaunchKernelGGL(k_oln, dim3(128), dim3(384), 0, stream,
                       ctxb, wT, bo, fused, lng, lnb, rw, wsum, part);
    hipLaunchKernelGGL(k_final, dim3(1), dim3(384), 0, stream, part, (float*)d_out);
}

// Round 5
// 168.363 us; speedup vs baseline: 5.1304x; 1.1122x over previous
//
#include <hip/hip_runtime.h>
#include <math.h>

#define Nn 4096
#define Ee 384
#define Hh 6
#define DHh 64
#define MIDm 96
#define TEe 1152
#define SPLIT 8

typedef short s16x8 __attribute__((ext_vector_type(8)));
typedef float f32x4 __attribute__((ext_vector_type(4)));
typedef float f32x16 __attribute__((ext_vector_type(16)));
typedef unsigned short ushort_t;
typedef unsigned short ushort4_t __attribute__((ext_vector_type(4)));

#define CROW(r, hf) ((((r) & 3)) + 8 * ((r) >> 2) + 4 * (hf))

__device__ __forceinline__ float gelu_exact(float x) {
    return 0.5f * x * (1.0f + erff(x * 0.70710678118654752f));
}
__device__ __forceinline__ float sigmoidf_(float x) {
    return 1.0f / (1.0f + __expf(-x));
}
__device__ __forceinline__ ushort_t f2bf(float x) {
    unsigned int u = __float_as_uint(x);
    u = (u + 0x7FFFu + ((u >> 16) & 1u)) >> 16;
    return (ushort_t)u;
}
__device__ __forceinline__ float bf2f(ushort_t u) {
    return __uint_as_float(((unsigned int)u) << 16);
}
__device__ __forceinline__ unsigned int cvtpk(float a, float b) {
    unsigned int r;
    asm("v_cvt_pk_bf16_f32 %0, %1, %2" : "=v"(r) : "v"(a), "v"(b));
    return r;
}

// weight-region offsets (ushort units)
#define W1L_OFF 0
#define W1H_OFF 36864
#define W2L_OFF 73728
#define W2H_OFF 110592
#define WQKV_OFF 147456
#define WO_OFF 589824

// ---------------- kernel: convert + transpose weights / activations to bf16 ----------------
__global__ __launch_bounds__(256) void k_cvt(
    const float* __restrict__ low, const float* __restrict__ high,
    const float* __restrict__ lw1, const float* __restrict__ hw1,
    const float* __restrict__ lw2, const float* __restrict__ hw2,
    const float* __restrict__ wqkv, const float* __restrict__ wo,
    ushort_t* __restrict__ lowb, ushort_t* __restrict__ highb,
    ushort_t* __restrict__ wT) {
    const int NE = Nn * Ee;
    const int T1 = NE, T2 = 2 * NE;
    const int W1N = 36864, W2N = 36864, WQN = 442368, WON = 147456;
    const int T3 = T2 + W1N, T4 = T3 + W1N, T5 = T4 + W2N, T6 = T5 + W2N;
    const int T7 = T6 + WQN, T8 = T7 + WON;
    for (int i = blockIdx.x * 256 + threadIdx.x; i < T8; i += gridDim.x * 256) {
        if (i < T1) {
            lowb[i] = f2bf(low[i]);
        } else if (i < T2) {
            highb[i - T1] = f2bf(high[i - T1]);
        } else if (i < T3) {
            int j = i - T2, m = j / 384, k = j % 384;
            wT[W1L_OFF + j] = f2bf(lw1[k * MIDm + m]);
        } else if (i < T4) {
            int j = i - T3, m = j / 384, k = j % 384;
            wT[W1H_OFF + j] = f2bf(hw1[k * MIDm + m]);
        } else if (i < T5) {
            int j = i - T4, e = j / MIDm, m = j % MIDm;
            wT[W2L_OFF + j] = f2bf(lw2[m * Ee + e]);
        } else if (i < T6) {
            int j = i - T5, e = j / MIDm, m = j % MIDm;
            wT[W2H_OFF + j] = f2bf(hw2[m * Ee + e]);
        } else if (i < T7) {
            int j = i - T6, n = j / 384, k = j % 384;
            wT[WQKV_OFF + j] = f2bf(wqkv[k * TEe + n]);
        } else {
            int j = i - T7, n = j / 384, k = j % 384;
            wT[WO_OFF + j] = f2bf(wo[k * Ee + n]);
        }
    }
}

// ---------------- kernel: dual channel-MLP + layer fuse (16x16x32 MFMA) ----------------
// grid 256 x 256 thr (4 waves); 16 rows/block
// waves: GEMM1 -> (stream, k-half); GEMM2 -> (stream, n-half)
__global__ __launch_bounds__(256) void k_mlp(
    const float* __restrict__ low, const float* __restrict__ high,
    const ushort_t* __restrict__ lowb, const ushort_t* __restrict__ highb,
    const float* __restrict__ lf, const ushort_t* __restrict__ wT,
    const float* __restrict__ lb1, const float* __restrict__ lb2,
    const float* __restrict__ hb1, const float* __restrict__ hb2,
    ushort_t* __restrict__ fusedb) {
    __shared__ float redsg[6144];          // 24576 B: red f32[2][2][16][96]  (reused as Sg u16[2][16][384])
    __shared__ ushort_t Hs[2][16][104];
    float* red = redsg;
    ushort_t* Sg = (ushort_t*)redsg;
    const int t = threadIdx.x;
    const int w = t >> 6, l = t & 63, l15 = l & 15, g4 = l >> 4;
    const int st = w >> 1, kh = w & 1;
    const int rb = blockIdx.x * 16;
    const ushort_t* Xb = st ? highb : lowb;
    const ushort_t* w1T = wT + (st ? W1H_OFF : W1L_OFF);
    const ushort_t* w2T = wT + (st ? W2H_OFF : W2L_OFF);
    // ---- GEMM1 partial (K split across kh): 6 chains x 6 ksteps
    {
        f32x4 hA[6];
#pragma unroll
        for (int nt = 0; nt < 6; nt++) hA[nt] = (f32x4){0.f, 0.f, 0.f, 0.f};
        for (int ks = 0; ks < 6; ks++) {
            s16x8 af = *(const s16x8*)&Xb[(size_t)(rb + l15) * 384 + kh * 192 + ks * 32 + g4 * 8];
#pragma unroll
            for (int nt = 0; nt < 6; nt++) {
                s16x8 bf = *(const s16x8*)&w1T[(nt * 16 + l15) * 384 + kh * 192 + ks * 32 + g4 * 8];
                hA[nt] = __builtin_amdgcn_mfma_f32_16x16x32_bf16(af, bf, hA[nt], 0, 0, 0);
            }
        }
#pragma unroll
        for (int nt = 0; nt < 6; nt++)
#pragma unroll
            for (int r = 0; r < 4; r++)
                red[((st * 2 + kh) * 16 + g4 * 4 + r) * 96 + nt * 16 + l15] = hA[nt][r];
    }
    __syncthreads();
    // ---- combine K-halves + bias + gelu -> Hs bf16
    for (int idx = t; idx < 2 * 16 * 96; idx += 256) {
        const int st2 = idx / 1536, rem = idx % 1536;
        const int rowm = rem / 96, mc = rem % 96;
        const float v = red[((st2 * 2) * 16 + rowm) * 96 + mc] +
                        red[((st2 * 2 + 1) * 16 + rowm) * 96 + mc] +
                        (st2 ? hb1[mc] : lb1[mc]);
        Hs[st2][rowm][mc] = f2bf(gelu_exact(v));
    }
    __syncthreads();
    // ---- GEMM2: wave (st, nh=kh) covers 192 cols: 12 chains x 3 ksteps
    {
        const float* b2p = st ? hb2 : lb2;
        f32x4 sA[12];
#pragma unroll
        for (int nt = 0; nt < 12; nt++) sA[nt] = (f32x4){0.f, 0.f, 0.f, 0.f};
#pragma unroll
        for (int ks = 0; ks < 3; ks++) {
            s16x8 af = *(const s16x8*)&Hs[st][l15][ks * 32 + g4 * 8];
#pragma unroll
            for (int nt = 0; nt < 12; nt++) {
                s16x8 bf = *(const s16x8*)&w2T[(kh * 192 + nt * 16 + l15) * 96 + ks * 32 + g4 * 8];
                sA[nt] = __builtin_amdgcn_mfma_f32_16x16x32_bf16(af, bf, sA[nt], 0, 0, 0);
            }
        }
#pragma unroll
        for (int nt = 0; nt < 12; nt++) {
            const float bb = b2p[kh * 192 + nt * 16 + l15];
#pragma unroll
            for (int r = 0; r < 4; r++)
                Sg[(st * 16 + g4 * 4 + r) * 384 + kh * 192 + nt * 16 + l15] =
                    f2bf(sigmoidf_(sA[nt][r] + bb));
        }
    }
    __syncthreads();
    // ---- fuse epilogue
    {
        const float a0 = lf[0], a1 = lf[1];
        const float mx = fmaxf(a0, a1);
        const float e0 = __expf(a0 - mx), e1 = __expf(a1 - mx);
        const float inv = 1.0f / (e0 + e1);
        const float w0 = e0 * inv, w1v = e1 * inv;
        for (int base = t * 4; base < 16 * 384; base += 256 * 4) {
            const int row = base / 384, e0i = base % 384;
            const int gr = rb + row;
            f32x4 lo4 = *(const f32x4*)&low[(size_t)gr * 384 + e0i];
            f32x4 hi4 = *(const f32x4*)&high[(size_t)gr * 384 + e0i];
            ushort4_t s0 = *(const ushort4_t*)&Sg[row * 384 + e0i];
            ushort4_t s1 = *(const ushort4_t*)&Sg[(16 + row) * 384 + e0i];
            ushort4_t fb;
#pragma unroll
            for (int i = 0; i < 4; i++)
                fb[i] = f2bf(w0 * lo4[i] * bf2f(s0[i]) + w1v * hi4[i] * bf2f(s1[i]));
            *(ushort4_t*)&fusedb[(size_t)gr * 384 + e0i] = fb;
        }
    }
}

// ---------------- kernel: qkv projection (32x32x16 MFMA, no A-staging) ----------------
// grid (64, 6) x 256 thr (4 waves: mh x nh); q pre-scaled by 0.125*log2(e)
__global__ __launch_bounds__(256) void k_qkv(
    const ushort_t* __restrict__ fusedb, const ushort_t* __restrict__ wT,
    const float* __restrict__ bqkv,
    ushort_t* __restrict__ qb, ushort_t* __restrict__ kb, ushort_t* __restrict__ vtb) {
    __shared__ float tls[4][32][40];
    const int t = threadIdx.x;
    const int w = t >> 6, l = t & 63, ll = l & 31, hf = l >> 5;
    const int mh = w >> 1, nh = w & 1;
    const int rb = blockIdx.x * 64 + mh * 32;
    const int cb = blockIdx.y * 192 + nh * 96;
    const ushort_t* wq = wT + WQKV_OFF;
    f32x16 acc[3];
#pragma unroll
    for (int nt = 0; nt < 3; nt++)
#pragma unroll
        for (int r = 0; r < 16; r++) acc[nt][r] = 0.0f;
    for (int ks = 0; ks < 24; ks++) {
        s16x8 af = *(const s16x8*)&fusedb[(size_t)(rb + ll) * 384 + ks * 16 + hf * 8];
#pragma unroll
        for (int nt = 0; nt < 3; nt++) {
            s16x8 bf = *(const s16x8*)&wq[(size_t)(cb + nt * 32 + ll) * 384 + ks * 16 + hf * 8];
            acc[nt] = __builtin_amdgcn_mfma_f32_32x32x16_bf16(af, bf, acc[nt], 0, 0, 0);
        }
    }
#pragma unroll
    for (int nt = 0; nt < 3; nt++) {
        const int nb = cb + nt * 32;
        const int which = nb / 384, wn = nb % 384;
        const int hb = wn >> 6, d0 = wn & 63;
        const float bias = bqkv[nb + ll];
        if (which == 2) {
            const int d = d0 + ll;
#pragma unroll
            for (int g2 = 0; g2 < 4; g2++) {
                ushort4_t u4;
#pragma unroll
                for (int i2 = 0; i2 < 4; i2++) u4[i2] = f2bf(acc[nt][g2 * 4 + i2] + bias);
                *(ushort4_t*)&vtb[((size_t)(hb * 64 + d)) * Nn + rb + 8 * g2 + 4 * hf] = u4;
            }
        } else {
            const float sc = (which == 0) ? 0.18033688f : 1.0f;  // 0.125*log2(e) on q
#pragma unroll
            for (int r = 0; r < 16; r++) tls[w][CROW(r, hf)][ll] = (acc[nt][r] + bias) * sc;
            ushort_t* dst = which ? kb : qb;
            const int row2 = l >> 1, sg = l & 1;
            union { ushort_t us[16]; s16x8 v[2]; } u;
#pragma unroll
            for (int j = 0; j < 16; j++) u.us[j] = f2bf(tls[w][row2][sg * 16 + j]);
            size_t base = ((size_t)hb * Nn + rb + row2) * 64 + d0 + sg * 16;
            *(s16x8*)&dst[base] = u.v[0];
            *(s16x8*)&dst[base + 8] = u.v[1];
        }
    }
}

// ---------------- kernel: flash attention, 32x32x16 MFMA, exp2-domain, split-K ----------------
// grid (32, 6, SPLIT) x 256 thr (4 waves x 32 q-rows); KV tile 64; bf16 partials
__global__ __launch_bounds__(256) void k_attn(
    const ushort_t* __restrict__ qb, const ushort_t* __restrict__ kb,
    const ushort_t* __restrict__ vtb, ushort_t* __restrict__ pof,
    float* __restrict__ pml) {
    __shared__ ushort_t Kt[64 * 64];
    __shared__ ushort_t Vt[64 * 64];
    const int t = threadIdx.x;
    const int wid = t >> 6, l = t & 63, ll = l & 31, hf = l >> 5;
    const int h = blockIdx.y, qt = blockIdx.x, sp = blockIdx.z;
    const int qrow0 = qt * 128 + wid * 32;
    s16x8 qf[4];
#pragma unroll
    for (int dc = 0; dc < 4; dc++)
        qf[dc] = *(const s16x8*)&qb[((size_t)h * Nn + qrow0 + ll) * 64 + dc * 16 + hf * 8];
    f32x16 o0, o1;
#pragma unroll
    for (int r = 0; r < 16; r++) { o0[r] = 0.0f; o1[r] = 0.0f; }
    float m = -1e30f, lsum = 0.0f;
    for (int kt = 0; kt < Nn / (64 * SPLIT); kt++) {
        const int ktb = (sp * (Nn / (64 * SPLIT)) + kt) * 64;
        __syncthreads();
        for (int j = t; j < 512; j += 256) {
            const int row = j >> 3, colE = (j & 7) * 8;
            const int off = row * 64 + (colE ^ ((row & 7) << 3));
            *(s16x8*)&Kt[off] = *(const s16x8*)&kb[((size_t)h * Nn + ktb + row) * 64 + colE];
            *(s16x8*)&Vt[off] = *(const s16x8*)&vtb[((size_t)h * 64 + row) * Nn + ktb + colE];
        }
        __syncthreads();
        f32x16 s0, s1;
#pragma unroll
        for (int r = 0; r < 16; r++) { s0[r] = 0.0f; s1[r] = 0.0f; }
#pragma unroll
        for (int dc = 0; dc < 4; dc++) {
            const int colE = dc * 16 + hf * 8;
            s16x8 kf0 = *(const s16x8*)&Kt[ll * 64 + (colE ^ ((ll & 7) << 3))];
            s16x8 kf1 = *(const s16x8*)&Kt[(32 + ll) * 64 + (colE ^ ((ll & 7) << 3))];
            s0 = __builtin_amdgcn_mfma_f32_32x32x16_bf16(kf0, qf[dc], s0, 0, 0, 0);
            s1 = __builtin_amdgcn_mfma_f32_32x32x16_bf16(kf1, qf[dc], s1, 0, 0, 0);
        }
        float mloc = s0[0];
#pragma unroll
        for (int r = 1; r < 16; r++) mloc = fmaxf(mloc, s0[r]);
#pragma unroll
        for (int r = 0; r < 16; r++) mloc = fmaxf(mloc, s1[r]);
        mloc = fmaxf(mloc, __shfl_xor(mloc, 32, 64));
        if (!__all(mloc <= m + 11.5f)) {
            const float mnew = fmaxf(m, mloc);
            const float scl = exp2f(m - mnew);
            m = mnew;
            lsum *= scl;
#pragma unroll
            for (int r = 0; r < 16; r++) { o0[r] *= scl; o1[r] *= scl; }
        }
        float ls = 0.0f;
#pragma unroll
        for (int r = 0; r < 16; r++) { s0[r] = exp2f(s0[r] - m); ls += s0[r]; }
#pragma unroll
        for (int r = 0; r < 16; r++) { s1[r] = exp2f(s1[r] - m); ls += s1[r]; }
        ls += __shfl_xor(ls, 32, 64);
        lsum += ls;
#pragma unroll
        for (int ks = 0; ks < 4; ks++) {
            const f32x16 S = (ks < 2) ? s0 : s1;
            const int b = (ks & 1) * 8;
            unsigned int t1 = cvtpk(S[b + 0], S[b + 1]);
            unsigned int t3 = cvtpk(S[b + 2], S[b + 3]);
            unsigned int t2 = cvtpk(S[b + 4], S[b + 5]);
            unsigned int t4 = cvtpk(S[b + 6], S[b + 7]);
            unsigned int t1p = __shfl_xor(t1, 32, 64);
            unsigned int t2p = __shfl_xor(t2, 32, 64);
            unsigned int t3p = __shfl_xor(t3, 32, 64);
            unsigned int t4p = __shfl_xor(t4, 32, 64);
            union { unsigned int w[4]; s16x8 v; } u;
            u.w[0] = hf ? t2p : t1;
            u.w[1] = hf ? t4p : t3;
            u.w[2] = hf ? t2 : t1p;
            u.w[3] = hf ? t4 : t3p;
            const int colE = ks * 16 + hf * 8;
            s16x8 vf0 = *(const s16x8*)&Vt[ll * 64 + (colE ^ ((ll & 7) << 3))];
            s16x8 vf1 = *(const s16x8*)&Vt[(32 + ll) * 64 + (colE ^ ((ll & 7) << 3))];
            o0 = __builtin_amdgcn_mfma_f32_32x32x16_bf16(vf0, u.v, o0, 0, 0, 0);
            o1 = __builtin_amdgcn_mfma_f32_32x32x16_bf16(vf1, u.v, o1, 0, 0, 0);
        }
    }
#pragma unroll
    for (int r = 0; r < 16; r++) {
        const int d_a = CROW(r, hf), d_b = 32 + CROW(r, hf);
        pof[((size_t)(sp * Ee + h * 64 + d_a)) * Nn + qrow0 + ll] = f2bf(o0[r]);
        pof[((size_t)(sp * Ee + h * 64 + d_b)) * Nn + qrow0 + ll] = f2bf(o1[r]);
    }
    if (hf == 0) {
        const size_t ix = 2 * (((size_t)sp * Hh + h) * Nn + qrow0 + ll);
        pml[ix] = m;
        pml[ix + 1] = lsum;
    }
}

// ---------------- kernel: split-K merge -> ctx bf16 [N][E] ----------------
// grid (64, 4) x 256; block = 64 q-rows x 96-col quarter
__global__ __launch_bounds__(256) void k_merge(
    const ushort_t* __restrict__ pof, const float* __restrict__ pml,
    ushort_t* __restrict__ ctxb) {
    __shared__ float mls[SPLIT][Hh][64][2];
    __shared__ float wls[SPLIT][Hh][64];
    __shared__ ushort_t tile[64][96];
    const int t = threadIdx.x;
    const int qb0 = blockIdx.x * 64;
    const int eq = blockIdx.y;
    for (int i = t; i < SPLIT * Hh * 64; i += 256) {
        const int s = i / (Hh * 64), r2 = i % (Hh * 64);
        const int hh = r2 / 64, qq = r2 % 64;
        const size_t ix = 2 * (((size_t)s * Hh + hh) * Nn + qb0 + qq);
        mls[s][hh][qq][0] = pml[ix];
        mls[s][hh][qq][1] = pml[ix + 1];
    }
    __syncthreads();
    for (int i = t; i < Hh * 64; i += 256) {
        const int hh = i / 64, qq = i % 64;
        float M = mls[0][hh][qq][0];
#pragma unroll
        for (int s = 1; s < SPLIT; s++) M = fmaxf(M, mls[s][hh][qq][0]);
        float den = 0.0f;
#pragma unroll
        for (int s = 0; s < SPLIT; s++) den += exp2f(mls[s][hh][qq][0] - M) * mls[s][hh][qq][1];
        const float dinv = 1.0f / den;
#pragma unroll
        for (int s = 0; s < SPLIT; s++) wls[s][hh][qq] = exp2f(mls[s][hh][qq][0] - M) * dinv;
    }
    __syncthreads();
    const int qq = t & 63, e0 = t >> 6;
    for (int i = 0; i < 24; i++) {
        const int el = e0 + 4 * i;
        const int e = eq * 96 + el;
        const int hh = e >> 6;
        float acc = 0.0f;
#pragma unroll
        for (int s = 0; s < SPLIT; s++)
            acc += wls[s][hh][qq] * bf2f(pof[((size_t)(s * Ee + e)) * Nn + qb0 + qq]);
        tile[qq][el] = f2bf(acc);
    }
    __syncthreads();
    for (int i = t; i < 64 * 12; i += 256) {
        const int q2 = i / 12, sg = i % 12;
        *(s16x8*)&ctxb[((size_t)(qb0 + q2)) * 384 + eq * 96 + sg * 8] =
            *(const s16x8*)&tile[q2][sg * 8];
    }
}

// ---------------- kernel: out-proj + bf16 residual + LayerNorm + weighted partials ----------------
// grid 256 x 256 thr (4 waves); 16 rows/block; 16x16x32 MFMA, 6 chains/wave
__global__ __launch_bounds__(256) void k_oln(
    const ushort_t* __restrict__ ctxb, const ushort_t* __restrict__ wT,
    const float* __restrict__ bo, const ushort_t* __restrict__ fusedb,
    const float* __restrict__ lng, const float* __restrict__ lnb,
    const float* __restrict__ rw, float* __restrict__ part) {
    __shared__ float xs[16][388];
    __shared__ float stats[16][2];
    const int t = threadIdx.x;
    const int w = t >> 6, l = t & 63, l15 = l & 15, g4 = l >> 4;
    const int rb = blockIdx.x * 16;
    const ushort_t* woT = wT + WO_OFF;
    f32x4 oA[6];
#pragma unroll
    for (int nt = 0; nt < 6; nt++) oA[nt] = (f32x4){0.f, 0.f, 0.f, 0.f};
    for (int ks = 0; ks < 12; ks++) {
        s16x8 af = *(const s16x8*)&ctxb[(size_t)(rb + l15) * 384 + ks * 32 + g4 * 8];
#pragma unroll
        for (int nt = 0; nt < 6; nt++) {
            s16x8 bf = *(const s16x8*)&woT[(size_t)(w * 96 + nt * 16 + l15) * 384 + ks * 32 + g4 * 8];
            oA[nt] = __builtin_amdgcn_mfma_f32_16x16x32_bf16(af, bf, oA[nt], 0, 0, 0);
        }
    }
#pragma unroll
    for (int nt = 0; nt < 6; nt++) {
        const int col = w * 96 + nt * 16 + l15;
        const float bias = bo[col];
#pragma unroll
        for (int r = 0; r < 4; r++) {
            const int row = g4 * 4 + r;
            xs[row][col] = oA[nt][r] + bias + bf2f(fusedb[(size_t)(rb + row) * 384 + col]);
        }
    }
    __syncthreads();
    {
        const int row = t >> 4, j = t & 15;
        float s1 = 0.0f, s2 = 0.0f;
        for (int i = 0; i < 24; i++) {
            const float x = xs[row][j + 16 * i];
            s1 += x;
            s2 += x * x;
        }
#pragma unroll
        for (int off = 1; off < 16; off <<= 1) {
            s1 += __shfl_xor(s1, off, 64);
            s2 += __shfl_xor(s2, off, 64);
        }
        if (j == 0) {
            const float mu = s1 * (1.0f / Ee);
            const float var = s2 * (1.0f / Ee) - mu * mu;
            stats[row][0] = mu;
            stats[row][1] = rsqrtf(var + 1e-5f);
        }
    }
    __syncthreads();
    for (int c = t; c < 384; c += 256) {
        const float gt = lng[c], bb = lnb[c];
        float acc = 0.0f;
        for (int r = 0; r < 16; r++) {
            const float xn = (xs[r][c] - stats[r][0]) * stats[r][1] * gt + bb;
            acc += xn * rw[rb + r];
        }
        part[(size_t)blockIdx.x * Ee + c] = acc;
    }
}

// ---------------- kernel: ordered partial reduce + L2 normalize (winv folded into eps) ----------------
__global__ __launch_bounds__(384) void k_final(const float* __restrict__ part,
                                               const float* __restrict__ rw,
                                               float* __restrict__ outp) {
    __shared__ float red[6], redw[6];
    const int t = threadIdx.x;
    float s = 0.0f;
    for (int b = 0; b < 256; b++) s += part[(size_t)b * Ee + t];
    float wsp = 0.0f;
    for (int i = t; i < Nn; i += 384) wsp += rw[i];
    float q2 = s * s;
#pragma unroll
    for (int off = 32; off > 0; off >>= 1) {
        q2 += __shfl_down(q2, off, 64);
        wsp += __shfl_down(wsp, off, 64);
    }
    const int wid = t >> 6, lane = t & 63;
    if (lane == 0) { red[wid] = q2; redw[wid] = wsp; }
    __syncthreads();
    float tot = 0.0f, wtot = 0.0f;
#pragma unroll
    for (int w = 0; w < 6; w++) { tot += red[w]; wtot += redw[w]; }
    outp[t] = s / (sqrtf(tot) + 1e-8f * wtot);
}

extern "C" void kernel_launch(void* const* d_in, const int* in_sizes, int n_in,
                              void* d_out, int out_size, void* d_ws, size_t ws_size,
                              hipStream_t stream) {
    const float* low  = (const float*)d_in[0];
    const float* high = (const float*)d_in[1];
    const float* rw   = (const float*)d_in[2];
    const float* lw1  = (const float*)d_in[3];
    const float* lb1  = (const float*)d_in[4];
    const float* lw2  = (const float*)d_in[5];
    const float* lb2  = (const float*)d_in[6];
    const float* hw1  = (const float*)d_in[7];
    const float* hb1  = (const float*)d_in[8];
    const float* hw2  = (const float*)d_in[9];
    const float* hb2  = (const float*)d_in[10];
    const float* lf   = (const float*)d_in[11];
    const float* wqkv = (const float*)d_in[12];
    const float* bqkv = (const float*)d_in[13];
    const float* wo   = (const float*)d_in[14];
    const float* bo   = (const float*)d_in[15];
    const float* lng  = (const float*)d_in[16];
    const float* lnb  = (const float*)d_in[17];

    float* ws = (float*)d_ws;
    const size_t NE = (size_t)Nn * Ee;
    float* pml  = ws;                      // 2*SPLIT*Hh*Nn = 393216 f32
    float* part = ws + 393216;             // 256*384 = 98304 f32
    ushort_t* u16base = (ushort_t*)(ws + 491520);
    ushort_t* lowb   = u16base;
    ushort_t* highb  = u16base + NE;
    ushort_t* fusedb = u16base + 2 * NE;
    ushort_t* vtb    = u16base + 3 * NE;
    ushort_t* qb     = u16base + 4 * NE;
    ushort_t* kb     = u16base + 5 * NE;
    ushort_t* ctxb   = u16base + 6 * NE;
    ushort_t* wT     = u16base + 7 * NE;   // 737280
    ushort_t* pof    = wT + 737280;        // SPLIT*Ee*Nn

    hipLaunchKernelGGL(k_cvt, dim3(1024), dim3(256), 0, stream,
                       low, high, lw1, hw1, lw2, hw2, wqkv, wo, lowb, highb, wT);
    hipLaunchKernelGGL(k_mlp, dim3(256), dim3(256), 0, stream,
                       low, high, lowb, highb, lf, wT, lb1, lb2, hb1, hb2, fusedb);
    hipLaunchKernelGGL(k_qkv, dim3(64, 6), dim3(256), 0, stream,
                       fusedb, wT, bqkv, qb, kb, vtb);
    hipLaunchKernelGGL(k_attn, dim3(32, Hh, SPLIT), dim3(256), 0, stream,
                       qb, kb, vtb, pof, pml);
    hipLaunchKernelGGL(k_merge, dim3(64, 4), dim3(256), 0, stream, pof, pml, ctxb);
    hipLaunchKernelGGL(k_oln, dim3(256), dim3(256), 0, stream,
                       ctxb, wT, bo, fusedb, lng, lnb, rw, part);
    hipLaunchKernelGGL(k_final, dim3(1), dim3(384), 0, stream, part, rw, (float*)d_out);
}

// Round 6
// 159.808 us; speedup vs baseline: 5.4051x; 1.0535x over previous
//
#include <hip/hip_runtime.h>
#include <math.h>

#define Nn 4096
#define Ee 384
#define Hh 6
#define DHh 64
#define MIDm 96
#define TEe 1152
#define SPLIT 8

typedef short s16x8 __attribute__((ext_vector_type(8)));
typedef float f32x4 __attribute__((ext_vector_type(4)));
typedef float f32x16 __attribute__((ext_vector_type(16)));
typedef unsigned short ushort_t;
typedef unsigned short ushort4_t __attribute__((ext_vector_type(4)));

#define CROW(r, hf) ((((r) & 3)) + 8 * ((r) >> 2) + 4 * (hf))

__device__ __forceinline__ float gelu_exact(float x) {
    return 0.5f * x * (1.0f + erff(x * 0.70710678118654752f));
}
__device__ __forceinline__ float sigmoidf_(float x) {
    return 1.0f / (1.0f + __expf(-x));
}
__device__ __forceinline__ ushort_t f2bf(float x) {
    unsigned int u = __float_as_uint(x);
    u = (u + 0x7FFFu + ((u >> 16) & 1u)) >> 16;
    return (ushort_t)u;
}
__device__ __forceinline__ float bf2f(ushort_t u) {
    return __uint_as_float(((unsigned int)u) << 16);
}
__device__ __forceinline__ unsigned int cvtpk(float a, float b) {
    unsigned int r;
    asm("v_cvt_pk_bf16_f32 %0, %1, %2" : "=v"(r) : "v"(a), "v"(b));
    return r;
}

// weight-region offsets (ushort units)
#define W1L_OFF 0
#define W1H_OFF 36864
#define W2L_OFF 73728
#define W2H_OFF 110592
#define WQKV_OFF 147456
#define WO_OFF 589824

// ---------------- kernel: convert + transpose weights to bf16 ----------------
__global__ __launch_bounds__(256) void k_cvt(
    const float* __restrict__ lw1, const float* __restrict__ hw1,
    const float* __restrict__ lw2, const float* __restrict__ hw2,
    const float* __restrict__ wqkv, const float* __restrict__ wo,
    ushort_t* __restrict__ wT) {
    const int W1N = 36864, W2N = 36864, WQN = 442368, WON = 147456;
    const int T1 = W1N, T2 = 2 * W1N, T3 = T2 + W2N, T4 = T3 + W2N;
    const int T5 = T4 + WQN, T6 = T5 + WON;
    for (int i = blockIdx.x * 256 + threadIdx.x; i < T6; i += gridDim.x * 256) {
        if (i < T1) {
            int m = i / 384, k = i % 384;
            wT[W1L_OFF + i] = f2bf(lw1[k * MIDm + m]);
        } else if (i < T2) {
            int j = i - T1, m = j / 384, k = j % 384;
            wT[W1H_OFF + j] = f2bf(hw1[k * MIDm + m]);
        } else if (i < T3) {
            int j = i - T2, e = j / MIDm, m = j % MIDm;
            wT[W2L_OFF + j] = f2bf(lw2[m * Ee + e]);
        } else if (i < T4) {
            int j = i - T3, e = j / MIDm, m = j % MIDm;
            wT[W2H_OFF + j] = f2bf(hw2[m * Ee + e]);
        } else if (i < T5) {
            int j = i - T4, n = j / 384, k = j % 384;
            wT[WQKV_OFF + j] = f2bf(wqkv[k * TEe + n]);
        } else {
            int j = i - T5, n = j / 384, k = j % 384;
            wT[WO_OFF + j] = f2bf(wo[k * Ee + n]);
        }
    }
}

// ---------------- kernel: dual channel-MLP + layer fuse (16x16x32 MFMA) ----------------
// grid 256 x 256 thr (4 waves); 16 rows/block; A-fragments converted inline from f32
__global__ __launch_bounds__(256) void k_mlp(
    const float* __restrict__ low, const float* __restrict__ high,
    const float* __restrict__ lf, const ushort_t* __restrict__ wT,
    const float* __restrict__ lb1, const float* __restrict__ lb2,
    const float* __restrict__ hb1, const float* __restrict__ hb2,
    ushort_t* __restrict__ fusedb) {
    __shared__ float redsg[6144];          // 24576 B: red f32[2][2][16][96] (reused as Sg u16[2][16][384])
    __shared__ ushort_t Hs[2][16][104];
    float* red = redsg;
    ushort_t* Sg = (ushort_t*)redsg;
    const int t = threadIdx.x;
    const int w = t >> 6, l = t & 63, l15 = l & 15, g4 = l >> 4;
    const int st = w >> 1, kh = w & 1;
    const int rb = blockIdx.x * 16;
    const float* Xf = st ? high : low;
    const ushort_t* w1T = wT + (st ? W1H_OFF : W1L_OFF);
    const ushort_t* w2T = wT + (st ? W2H_OFF : W2L_OFF);
    // ---- GEMM1 partial (K split across kh): 6 chains x 6 ksteps
    {
        f32x4 hA[6];
#pragma unroll
        for (int nt = 0; nt < 6; nt++) hA[nt] = (f32x4){0.f, 0.f, 0.f, 0.f};
        for (int ks = 0; ks < 6; ks++) {
            const float* ap = &Xf[(size_t)(rb + l15) * 384 + kh * 192 + ks * 32 + g4 * 8];
            f32x4 a0 = *(const f32x4*)ap;
            f32x4 a1 = *(const f32x4*)(ap + 4);
            union { unsigned int uw[4]; s16x8 v; } ua;
            ua.uw[0] = cvtpk(a0[0], a0[1]);
            ua.uw[1] = cvtpk(a0[2], a0[3]);
            ua.uw[2] = cvtpk(a1[0], a1[1]);
            ua.uw[3] = cvtpk(a1[2], a1[3]);
#pragma unroll
            for (int nt = 0; nt < 6; nt++) {
                s16x8 bf = *(const s16x8*)&w1T[(nt * 16 + l15) * 384 + kh * 192 + ks * 32 + g4 * 8];
                hA[nt] = __builtin_amdgcn_mfma_f32_16x16x32_bf16(ua.v, bf, hA[nt], 0, 0, 0);
            }
        }
#pragma unroll
        for (int nt = 0; nt < 6; nt++)
#pragma unroll
            for (int r = 0; r < 4; r++)
                red[((st * 2 + kh) * 16 + g4 * 4 + r) * 96 + nt * 16 + l15] = hA[nt][r];
    }
    __syncthreads();
    // ---- combine K-halves + bias + gelu -> Hs bf16
    for (int idx = t; idx < 2 * 16 * 96; idx += 256) {
        const int st2 = idx / 1536, rem = idx % 1536;
        const int rowm = rem / 96, mc = rem % 96;
        const float v = red[((st2 * 2) * 16 + rowm) * 96 + mc] +
                        red[((st2 * 2 + 1) * 16 + rowm) * 96 + mc] +
                        (st2 ? hb1[mc] : lb1[mc]);
        Hs[st2][rowm][mc] = f2bf(gelu_exact(v));
    }
    __syncthreads();
    // ---- GEMM2: wave (st, nh=kh) covers 192 cols: 12 chains x 3 ksteps
    {
        const float* b2p = st ? hb2 : lb2;
        f32x4 sA[12];
#pragma unroll
        for (int nt = 0; nt < 12; nt++) sA[nt] = (f32x4){0.f, 0.f, 0.f, 0.f};
#pragma unroll
        for (int ks = 0; ks < 3; ks++) {
            s16x8 af = *(const s16x8*)&Hs[st][l15][ks * 32 + g4 * 8];
#pragma unroll
            for (int nt = 0; nt < 12; nt++) {
                s16x8 bf = *(const s16x8*)&w2T[(kh * 192 + nt * 16 + l15) * 96 + ks * 32 + g4 * 8];
                sA[nt] = __builtin_amdgcn_mfma_f32_16x16x32_bf16(af, bf, sA[nt], 0, 0, 0);
            }
        }
#pragma unroll
        for (int nt = 0; nt < 12; nt++) {
            const float bb = b2p[kh * 192 + nt * 16 + l15];
#pragma unroll
            for (int r = 0; r < 4; r++)
                Sg[(st * 16 + g4 * 4 + r) * 384 + kh * 192 + nt * 16 + l15] =
                    f2bf(sigmoidf_(sA[nt][r] + bb));
        }
    }
    __syncthreads();
    // ---- fuse epilogue
    {
        const float a0 = lf[0], a1 = lf[1];
        const float mx = fmaxf(a0, a1);
        const float e0 = __expf(a0 - mx), e1 = __expf(a1 - mx);
        const float inv = 1.0f / (e0 + e1);
        const float w0 = e0 * inv, w1v = e1 * inv;
        for (int base = t * 4; base < 16 * 384; base += 256 * 4) {
            const int row = base / 384, e0i = base % 384;
            const int gr = rb + row;
            f32x4 lo4 = *(const f32x4*)&low[(size_t)gr * 384 + e0i];
            f32x4 hi4 = *(const f32x4*)&high[(size_t)gr * 384 + e0i];
            ushort4_t s0 = *(const ushort4_t*)&Sg[row * 384 + e0i];
            ushort4_t s1 = *(const ushort4_t*)&Sg[(16 + row) * 384 + e0i];
            ushort4_t fb;
#pragma unroll
            for (int i = 0; i < 4; i++)
                fb[i] = f2bf(w0 * lo4[i] * bf2f(s0[i]) + w1v * hi4[i] * bf2f(s1[i]));
            *(ushort4_t*)&fusedb[(size_t)gr * 384 + e0i] = fb;
        }
    }
}

// ---------------- kernel: qkv projection (32x32x16 MFMA, no A-staging) ----------------
// grid (64, 6) x 256 thr (4 waves: mh x nh); q pre-scaled by 0.125*log2(e)
__global__ __launch_bounds__(256) void k_qkv(
    const ushort_t* __restrict__ fusedb, const ushort_t* __restrict__ wT,
    const float* __restrict__ bqkv,
    ushort_t* __restrict__ qb, ushort_t* __restrict__ kb, ushort_t* __restrict__ vtb) {
    __shared__ float tls[4][32][40];
    const int t = threadIdx.x;
    const int w = t >> 6, l = t & 63, ll = l & 31, hf = l >> 5;
    const int mh = w >> 1, nh = w & 1;
    const int rb = blockIdx.x * 64 + mh * 32;
    const int cb = blockIdx.y * 192 + nh * 96;
    const ushort_t* wq = wT + WQKV_OFF;
    f32x16 acc[3];
#pragma unroll
    for (int nt = 0; nt < 3; nt++)
#pragma unroll
        for (int r = 0; r < 16; r++) acc[nt][r] = 0.0f;
    for (int ks = 0; ks < 24; ks++) {
        s16x8 af = *(const s16x8*)&fusedb[(size_t)(rb + ll) * 384 + ks * 16 + hf * 8];
#pragma unroll
        for (int nt = 0; nt < 3; nt++) {
            s16x8 bf = *(const s16x8*)&wq[(size_t)(cb + nt * 32 + ll) * 384 + ks * 16 + hf * 8];
            acc[nt] = __builtin_amdgcn_mfma_f32_32x32x16_bf16(af, bf, acc[nt], 0, 0, 0);
        }
    }
#pragma unroll
    for (int nt = 0; nt < 3; nt++) {
        const int nb = cb + nt * 32;
        const int which = nb / 384, wn = nb % 384;
        const int hb = wn >> 6, d0 = wn & 63;
        const float bias = bqkv[nb + ll];
        if (which == 2) {
            const int d = d0 + ll;
#pragma unroll
            for (int g2 = 0; g2 < 4; g2++) {
                ushort4_t u4;
#pragma unroll
                for (int i2 = 0; i2 < 4; i2++) u4[i2] = f2bf(acc[nt][g2 * 4 + i2] + bias);
                *(ushort4_t*)&vtb[((size_t)(hb * 64 + d)) * Nn + rb + 8 * g2 + 4 * hf] = u4;
            }
        } else {
            const float sc = (which == 0) ? 0.18033688f : 1.0f;  // 0.125*log2(e) on q
#pragma unroll
            for (int r = 0; r < 16; r++) tls[w][CROW(r, hf)][ll] = (acc[nt][r] + bias) * sc;
            ushort_t* dst = which ? kb : qb;
            const int row2 = l >> 1, sg = l & 1;
            union { ushort_t us[16]; s16x8 v[2]; } u;
#pragma unroll
            for (int j = 0; j < 16; j++) u.us[j] = f2bf(tls[w][row2][sg * 16 + j]);
            size_t base = ((size_t)hb * Nn + rb + row2) * 64 + d0 + sg * 16;
            *(s16x8*)&dst[base] = u.v[0];
            *(s16x8*)&dst[base + 8] = u.v[1];
        }
    }
}

// ---------------- kernel: flash attention, softmax-free (m=0), 32x32x16 MFMA, split-K ----------------
// grid (32, 6, SPLIT) x 256 thr (4 waves x 32 q-rows); KV tile 64; bf16 partials
__global__ __launch_bounds__(256) void k_attn(
    const ushort_t* __restrict__ qb, const ushort_t* __restrict__ kb,
    const ushort_t* __restrict__ vtb, ushort_t* __restrict__ pof,
    float* __restrict__ pml) {
    __shared__ ushort_t Kt[64 * 64];
    __shared__ ushort_t Vt[64 * 64];
    const int t = threadIdx.x;
    const int wid = t >> 6, l = t & 63, ll = l & 31, hf = l >> 5;
    const int h = blockIdx.y, qt = blockIdx.x, sp = blockIdx.z;
    const int qrow0 = qt * 128 + wid * 32;
    s16x8 qf[4];
#pragma unroll
    for (int dc = 0; dc < 4; dc++)
        qf[dc] = *(const s16x8*)&qb[((size_t)h * Nn + qrow0 + ll) * 64 + dc * 16 + hf * 8];
    f32x16 o0, o1;
#pragma unroll
    for (int r = 0; r < 16; r++) { o0[r] = 0.0f; o1[r] = 0.0f; }
    float lsum = 0.0f;
    for (int kt = 0; kt < Nn / (64 * SPLIT); kt++) {
        const int ktb = (sp * (Nn / (64 * SPLIT)) + kt) * 64;
        __syncthreads();
        for (int j = t; j < 512; j += 256) {
            const int row = j >> 3, colE = (j & 7) * 8;
            const int off = row * 64 + (colE ^ ((row & 7) << 3));
            *(s16x8*)&Kt[off] = *(const s16x8*)&kb[((size_t)h * Nn + ktb + row) * 64 + colE];
            *(s16x8*)&Vt[off] = *(const s16x8*)&vtb[((size_t)h * 64 + row) * Nn + ktb + colE];
        }
        __syncthreads();
        f32x16 s0, s1;
#pragma unroll
        for (int r = 0; r < 16; r++) { s0[r] = 0.0f; s1[r] = 0.0f; }
#pragma unroll
        for (int dc = 0; dc < 4; dc++) {
            const int colE = dc * 16 + hf * 8;
            s16x8 kf0 = *(const s16x8*)&Kt[ll * 64 + (colE ^ ((ll & 7) << 3))];
            s16x8 kf1 = *(const s16x8*)&Kt[(32 + ll) * 64 + (colE ^ ((ll & 7) << 3))];
            s0 = __builtin_amdgcn_mfma_f32_32x32x16_bf16(kf0, qf[dc], s0, 0, 0, 0);
            s1 = __builtin_amdgcn_mfma_f32_32x32x16_bf16(kf1, qf[dc], s1, 0, 0, 0);
        }
        // softmax-free: P = exp2(s) raw (global m=0; /lsum normalization cancels any shift)
        float ls = 0.0f;
#pragma unroll
        for (int r = 0; r < 16; r++) { s0[r] = exp2f(s0[r]); ls += s0[r]; }
#pragma unroll
        for (int r = 0; r < 16; r++) { s1[r] = exp2f(s1[r]); ls += s1[r]; }
        ls += __shfl_xor(ls, 32, 64);
        lsum += ls;
        // P^T fragments in-register: 2 shuffles per ks (lane pair exchange)
#pragma unroll
        for (int ks = 0; ks < 4; ks++) {
            const f32x16 S = (ks < 2) ? s0 : s1;
            const int b = (ks & 1) * 8;
            unsigned int t1 = cvtpk(S[b + 0], S[b + 1]);
            unsigned int t3 = cvtpk(S[b + 2], S[b + 3]);
            unsigned int t2 = cvtpk(S[b + 4], S[b + 5]);
            unsigned int t4 = cvtpk(S[b + 6], S[b + 7]);
            unsigned int x = __shfl_xor(hf ? t1 : t2, 32, 64);
            unsigned int y = __shfl_xor(hf ? t3 : t4, 32, 64);
            union { unsigned int uw[4]; s16x8 v; } u;
            u.uw[0] = hf ? x : t1;
            u.uw[1] = hf ? y : t3;
            u.uw[2] = hf ? t2 : x;
            u.uw[3] = hf ? t4 : y;
            const int colE = ks * 16 + hf * 8;
            s16x8 vf0 = *(const s16x8*)&Vt[ll * 64 + (colE ^ ((ll & 7) << 3))];
            s16x8 vf1 = *(const s16x8*)&Vt[(32 + ll) * 64 + (colE ^ ((ll & 7) << 3))];
            o0 = __builtin_amdgcn_mfma_f32_32x32x16_bf16(vf0, u.v, o0, 0, 0, 0);
            o1 = __builtin_amdgcn_mfma_f32_32x32x16_bf16(vf1, u.v, o1, 0, 0, 0);
        }
    }
#pragma unroll
    for (int r = 0; r < 16; r++) {
        const int d_a = CROW(r, hf), d_b = 32 + CROW(r, hf);
        pof[((size_t)(sp * Ee + h * 64 + d_a)) * Nn + qrow0 + ll] = f2bf(o0[r]);
        pof[((size_t)(sp * Ee + h * 64 + d_b)) * Nn + qrow0 + ll] = f2bf(o1[r]);
    }
    if (hf == 0)
        pml[((size_t)sp * Hh + h) * Nn + qrow0 + ll] = lsum;
}

// ---------------- kernel: split-K merge (uniform weights) -> ctx bf16 [N][E] ----------------
// grid (64, 4) x 256; block = 64 q-rows x 96-col quarter
__global__ __launch_bounds__(256) void k_merge(
    const ushort_t* __restrict__ pof, const float* __restrict__ pml,
    ushort_t* __restrict__ ctxb) {
    __shared__ float lsums[SPLIT][Hh][64];
    __shared__ float dinv[Hh][64];
    __shared__ ushort_t tile[64][96];
    const int t = threadIdx.x;
    const int qb0 = blockIdx.x * 64;
    const int eq = blockIdx.y;
    for (int i = t; i < SPLIT * Hh * 64; i += 256) {
        const int s = i / (Hh * 64), r2 = i % (Hh * 64);
        const int hh = r2 / 64, qq = r2 % 64;
        lsums[s][hh][qq] = pml[((size_t)s * Hh + hh) * Nn + qb0 + qq];
    }
    __syncthreads();
    for (int i = t; i < Hh * 64; i += 256) {
        const int hh = i / 64, qq = i % 64;
        float den = 0.0f;
#pragma unroll
        for (int s = 0; s < SPLIT; s++) den += lsums[s][hh][qq];
        dinv[hh][qq] = 1.0f / den;
    }
    __syncthreads();
    const int qq = t & 63, e0 = t >> 6;
    for (int i = 0; i < 24; i++) {
        const int el = e0 + 4 * i;
        const int e = eq * 96 + el;
        const int hh = e >> 6;
        float acc = 0.0f;
#pragma unroll
        for (int s = 0; s < SPLIT; s++)
            acc += bf2f(pof[((size_t)(s * Ee + e)) * Nn + qb0 + qq]);
        tile[qq][el] = f2bf(acc * dinv[hh][qq]);
    }
    __syncthreads();
    for (int i = t; i < 64 * 12; i += 256) {
        const int q2 = i / 12, sg = i % 12;
        *(s16x8*)&ctxb[((size_t)(qb0 + q2)) * 384 + eq * 96 + sg * 8] =
            *(const s16x8*)&tile[q2][sg * 8];
    }
}

// ---------------- kernel: out-proj + bf16 residual + LayerNorm + weighted partials ----------------
// grid 256 x 256 thr (4 waves); 16 rows/block; 16x16x32 MFMA, 6 chains/wave
__global__ __launch_bounds__(256) void k_oln(
    const ushort_t* __restrict__ ctxb, const ushort_t* __restrict__ wT,
    const float* __restrict__ bo, const ushort_t* __restrict__ fusedb,
    const float* __restrict__ lng, const float* __restrict__ lnb,
    const float* __restrict__ rw, float* __restrict__ part) {
    __shared__ float xs[16][388];
    __shared__ float stats[16][2];
    const int t = threadIdx.x;
    const int w = t >> 6, l = t & 63, l15 = l & 15, g4 = l >> 4;
    const int rb = blockIdx.x * 16;
    const ushort_t* woT = wT + WO_OFF;
    f32x4 oA[6];
#pragma unroll
    for (int nt = 0; nt < 6; nt++) oA[nt] = (f32x4){0.f, 0.f, 0.f, 0.f};
    for (int ks = 0; ks < 12; ks++) {
        s16x8 af = *(const s16x8*)&ctxb[(size_t)(rb + l15) * 384 + ks * 32 + g4 * 8];
#pragma unroll
        for (int nt = 0; nt < 6; nt++) {
            s16x8 bf = *(const s16x8*)&woT[(size_t)(w * 96 + nt * 16 + l15) * 384 + ks * 32 + g4 * 8];
            oA[nt] = __builtin_amdgcn_mfma_f32_16x16x32_bf16(af, bf, oA[nt], 0, 0, 0);
        }
    }
#pragma unroll
    for (int nt = 0; nt < 6; nt++) {
        const int col = w * 96 + nt * 16 + l15;
        const float bias = bo[col];
#pragma unroll
        for (int r = 0; r < 4; r++) {
            const int row = g4 * 4 + r;
            xs[row][col] = oA[nt][r] + bias + bf2f(fusedb[(size_t)(rb + row) * 384 + col]);
        }
    }
    __syncthreads();
    {
        const int row = t >> 4, j = t & 15;
        float s1 = 0.0f, s2 = 0.0f;
        for (int i = 0; i < 24; i++) {
            const float x = xs[row][j + 16 * i];
            s1 += x;
            s2 += x * x;
        }
#pragma unroll
        for (int off = 1; off < 16; off <<= 1) {
            s1 += __shfl_xor(s1, off, 64);
            s2 += __shfl_xor(s2, off, 64);
        }
        if (j == 0) {
            const float mu = s1 * (1.0f / Ee);
            const float var = s2 * (1.0f / Ee) - mu * mu;
            stats[row][0] = mu;
            stats[row][1] = rsqrtf(var + 1e-5f);
        }
    }
    __syncthreads();
    for (int c = t; c < 384; c += 256) {
        const float gt = lng[c], bb = lnb[c];
        float acc = 0.0f;
        for (int r = 0; r < 16; r++) {
            const float xn = (xs[r][c] - stats[r][0]) * stats[r][1] * gt + bb;
            acc += xn * rw[rb + r];
        }
        part[(size_t)blockIdx.x * Ee + c] = acc;
    }
}

// ---------------- kernel: ordered partial reduce + L2 normalize (winv folded into eps) ----------------
__global__ __launch_bounds__(384) void k_final(const float* __restrict__ part,
                                               const float* __restrict__ rw,
                                               float* __restrict__ outp) {
    __shared__ float red[6], redw[6];
    const int t = threadIdx.x;
    float s = 0.0f;
    for (int b = 0; b < 256; b++) s += part[(size_t)b * Ee + t];
    float wsp = 0.0f;
    for (int i = t; i < Nn; i += 384) wsp += rw[i];
    float q2 = s * s;
#pragma unroll
    for (int off = 32; off > 0; off >>= 1) {
        q2 += __shfl_down(q2, off, 64);
        wsp += __shfl_down(wsp, off, 64);
    }
    const int wid = t >> 6, lane = t & 63;
    if (lane == 0) { red[wid] = q2; redw[wid] = wsp; }
    __syncthreads();
    float tot = 0.0f, wtot = 0.0f;
#pragma unroll
    for (int w = 0; w < 6; w++) { tot += red[w]; wtot += redw[w]; }
    outp[t] = s / (sqrtf(tot) + 1e-8f * wtot);
}

extern "C" void kernel_launch(void* const* d_in, const int* in_sizes, int n_in,
                              void* d_out, int out_size, void* d_ws, size_t ws_size,
                              hipStream_t stream) {
    const float* low  = (const float*)d_in[0];
    const float* high = (const float*)d_in[1];
    const float* rw   = (const float*)d_in[2];
    const float* lw1  = (const float*)d_in[3];
    const float* lb1  = (const float*)d_in[4];
    const float* lw2  = (const float*)d_in[5];
    const float* lb2  = (const float*)d_in[6];
    const float* hw1  = (const float*)d_in[7];
    const float* hb1  = (const float*)d_in[8];
    const float* hw2  = (const float*)d_in[9];
    const float* hb2  = (const float*)d_in[10];
    const float* lf   = (const float*)d_in[11];
    const float* wqkv = (const float*)d_in[12];
    const float* bqkv = (const float*)d_in[13];
    const float* wo   = (const float*)d_in[14];
    const float* bo   = (const float*)d_in[15];
    const float* lng  = (const float*)d_in[16];
    const float* lnb  = (const float*)d_in[17];

    float* ws = (float*)d_ws;
    const size_t NE = (size_t)Nn * Ee;
    float* pml  = ws;                      // SPLIT*Hh*Nn = 196608 f32 (lsum only)
    float* part = ws + 196608;             // 256*384 = 98304 f32
    ushort_t* u16base = (ushort_t*)(ws + 294912);
    ushort_t* fusedb = u16base;
    ushort_t* vtb    = u16base + NE;
    ushort_t* qb     = u16base + 2 * NE;
    ushort_t* kb     = u16base + 3 * NE;
    ushort_t* ctxb   = u16base + 4 * NE;
    ushort_t* wT     = u16base + 5 * NE;   // 737280
    ushort_t* pof    = wT + 737280;        // SPLIT*Ee*Nn

    hipLaunchKernelGGL(k_cvt, dim3(512), dim3(256), 0, stream,
                       lw1, hw1, lw2, hw2, wqkv, wo, wT);
    hipLaunchKernelGGL(k_mlp, dim3(256), dim3(256), 0, stream,
                       low, high, lf, wT, lb1, lb2, hb1, hb2, fusedb);
    hipLaunchKernelGGL(k_qkv, dim3(64, 6), dim3(256), 0, stream,
                       fusedb, wT, bqkv, qb, kb, vtb);
    hipLaunchKernelGGL(k_attn, dim3(32, Hh, SPLIT), dim3(256), 0, stream,
                       qb, kb, vtb, pof, pml);
    hipLaunchKernelGGL(k_merge, dim3(64, 4), dim3(256), 0, stream, pof, pml, ctxb);
    hipLaunchKernelGGL(k_oln, dim3(256), dim3(256), 0, stream,
                       ctxb, wT, bo, fusedb, lng, lnb, rw, part);
    hipLaunchKernelGGL(k_final, dim3(1), dim3(384), 0, stream, part, rw, (float*)d_out);
}

// Round 7
// 147.901 us; speedup vs baseline: 5.8402x; 1.0805x over previous
//
#include <hip/hip_runtime.h>
#include <math.h>

#define Nn 4096
#define Ee 384
#define Hh 6
#define DHh 64
#define MIDm 96
#define TEe 1152
#define SPLIT 4

typedef short s16x8 __attribute__((ext_vector_type(8)));
typedef float f32x4 __attribute__((ext_vector_type(4)));
typedef float f32x16 __attribute__((ext_vector_type(16)));
typedef unsigned short ushort_t;
typedef unsigned short ushort4_t __attribute__((ext_vector_type(4)));

#define CROW(r, hf) ((((r) & 3)) + 8 * ((r) >> 2) + 4 * (hf))

__device__ __forceinline__ float gelu_exact(float x) {
    return 0.5f * x * (1.0f + erff(x * 0.70710678118654752f));
}
__device__ __forceinline__ float sigmoidf_(float x) {
    return 1.0f / (1.0f + __expf(-x));
}
__device__ __forceinline__ ushort_t f2bf(float x) {
    unsigned int u = __float_as_uint(x);
    u = (u + 0x7FFFu + ((u >> 16) & 1u)) >> 16;
    return (ushort_t)u;
}
__device__ __forceinline__ float bf2f(ushort_t u) {
    return __uint_as_float(((unsigned int)u) << 16);
}
__device__ __forceinline__ unsigned int cvtpk(float a, float b) {
    unsigned int r;
    asm("v_cvt_pk_bf16_f32 %0, %1, %2" : "=v"(r) : "v"(a), "v"(b));
    return r;
}

// weight-region offsets (ushort units)
#define W1L_OFF 0
#define W1H_OFF 36864
#define W2L_OFF 73728
#define W2H_OFF 110592
#define WQKV_OFF 147456
#define WO_OFF 589824

// ---------------- kernel: convert + transpose weights to bf16 ----------------
__global__ __launch_bounds__(256) void k_cvt(
    const float* __restrict__ lw1, const float* __restrict__ hw1,
    const float* __restrict__ lw2, const float* __restrict__ hw2,
    const float* __restrict__ wqkv, const float* __restrict__ wo,
    ushort_t* __restrict__ wT) {
    const int W1N = 36864, W2N = 36864, WQN = 442368, WON = 147456;
    const int T1 = W1N, T2 = 2 * W1N, T3 = T2 + W2N, T4 = T3 + W2N;
    const int T5 = T4 + WQN, T6 = T5 + WON;
    for (int i = blockIdx.x * 256 + threadIdx.x; i < T6; i += gridDim.x * 256) {
        if (i < T1) {
            int m = i / 384, k = i % 384;
            wT[W1L_OFF + i] = f2bf(lw1[k * MIDm + m]);
        } else if (i < T2) {
            int j = i - T1, m = j / 384, k = j % 384;
            wT[W1H_OFF + j] = f2bf(hw1[k * MIDm + m]);
        } else if (i < T3) {
            int j = i - T2, e = j / MIDm, m = j % MIDm;
            wT[W2L_OFF + j] = f2bf(lw2[m * Ee + e]);
        } else if (i < T4) {
            int j = i - T3, e = j / MIDm, m = j % MIDm;
            wT[W2H_OFF + j] = f2bf(hw2[m * Ee + e]);
        } else if (i < T5) {
            int j = i - T4, n = j / 384, k = j % 384;
            wT[WQKV_OFF + j] = f2bf(wqkv[k * TEe + n]);
        } else {
            int j = i - T5, n = j / 384, k = j % 384;
            wT[WO_OFF + j] = f2bf(wo[k * Ee + n]);
        }
    }
}

// ---------------- kernel: dual channel-MLP + layer fuse (16x16x32 MFMA) ----------------
// grid 256 x 256 thr (4 waves); 16 rows/block; A-fragments converted inline from f32
__global__ __launch_bounds__(256) void k_mlp(
    const float* __restrict__ low, const float* __restrict__ high,
    const float* __restrict__ lf, const ushort_t* __restrict__ wT,
    const float* __restrict__ lb1, const float* __restrict__ lb2,
    const float* __restrict__ hb1, const float* __restrict__ hb2,
    ushort_t* __restrict__ fusedb) {
    __shared__ float redsg[6144];          // 24576 B: red f32[2][2][16][96] (reused as Sg u16[2][16][384])
    __shared__ ushort_t Hs[2][16][104];
    float* red = redsg;
    ushort_t* Sg = (ushort_t*)redsg;
    const int t = threadIdx.x;
    const int w = t >> 6, l = t & 63, l15 = l & 15, g4 = l >> 4;
    const int st = w >> 1, kh = w & 1;
    const int rb = blockIdx.x * 16;
    const float* Xf = st ? high : low;
    const ushort_t* w1T = wT + (st ? W1H_OFF : W1L_OFF);
    const ushort_t* w2T = wT + (st ? W2H_OFF : W2L_OFF);
    // ---- GEMM1 partial (K split across kh): 6 chains x 6 ksteps
    {
        f32x4 hA[6];
#pragma unroll
        for (int nt = 0; nt < 6; nt++) hA[nt] = (f32x4){0.f, 0.f, 0.f, 0.f};
        for (int ks = 0; ks < 6; ks++) {
            const float* ap = &Xf[(size_t)(rb + l15) * 384 + kh * 192 + ks * 32 + g4 * 8];
            f32x4 a0 = *(const f32x4*)ap;
            f32x4 a1 = *(const f32x4*)(ap + 4);
            union { unsigned int uw[4]; s16x8 v; } ua;
            ua.uw[0] = cvtpk(a0[0], a0[1]);
            ua.uw[1] = cvtpk(a0[2], a0[3]);
            ua.uw[2] = cvtpk(a1[0], a1[1]);
            ua.uw[3] = cvtpk(a1[2], a1[3]);
#pragma unroll
            for (int nt = 0; nt < 6; nt++) {
                s16x8 bf = *(const s16x8*)&w1T[(nt * 16 + l15) * 384 + kh * 192 + ks * 32 + g4 * 8];
                hA[nt] = __builtin_amdgcn_mfma_f32_16x16x32_bf16(ua.v, bf, hA[nt], 0, 0, 0);
            }
        }
#pragma unroll
        for (int nt = 0; nt < 6; nt++)
#pragma unroll
            for (int r = 0; r < 4; r++)
                red[((st * 2 + kh) * 16 + g4 * 4 + r) * 96 + nt * 16 + l15] = hA[nt][r];
    }
    __syncthreads();
    // ---- combine K-halves + bias + gelu -> Hs bf16
    for (int idx = t; idx < 2 * 16 * 96; idx += 256) {
        const int st2 = idx / 1536, rem = idx % 1536;
        const int rowm = rem / 96, mc = rem % 96;
        const float v = red[((st2 * 2) * 16 + rowm) * 96 + mc] +
                        red[((st2 * 2 + 1) * 16 + rowm) * 96 + mc] +
                        (st2 ? hb1[mc] : lb1[mc]);
        Hs[st2][rowm][mc] = f2bf(gelu_exact(v));
    }
    __syncthreads();
    // ---- GEMM2: wave (st, nh=kh) covers 192 cols: 12 chains x 3 ksteps
    {
        const float* b2p = st ? hb2 : lb2;
        f32x4 sA[12];
#pragma unroll
        for (int nt = 0; nt < 12; nt++) sA[nt] = (f32x4){0.f, 0.f, 0.f, 0.f};
#pragma unroll
        for (int ks = 0; ks < 3; ks++) {
            s16x8 af = *(const s16x8*)&Hs[st][l15][ks * 32 + g4 * 8];
#pragma unroll
            for (int nt = 0; nt < 12; nt++) {
                s16x8 bf = *(const s16x8*)&w2T[(kh * 192 + nt * 16 + l15) * 96 + ks * 32 + g4 * 8];
                sA[nt] = __builtin_amdgcn_mfma_f32_16x16x32_bf16(af, bf, sA[nt], 0, 0, 0);
            }
        }
#pragma unroll
        for (int nt = 0; nt < 12; nt++) {
            const float bb = b2p[kh * 192 + nt * 16 + l15];
#pragma unroll
            for (int r = 0; r < 4; r++)
                Sg[(st * 16 + g4 * 4 + r) * 384 + kh * 192 + nt * 16 + l15] =
                    f2bf(sigmoidf_(sA[nt][r] + bb));
        }
    }
    __syncthreads();
    // ---- fuse epilogue
    {
        const float a0 = lf[0], a1 = lf[1];
        const float mx = fmaxf(a0, a1);
        const float e0 = __expf(a0 - mx), e1 = __expf(a1 - mx);
        const float inv = 1.0f / (e0 + e1);
        const float w0 = e0 * inv, w1v = e1 * inv;
        for (int base = t * 4; base < 16 * 384; base += 256 * 4) {
            const int row = base / 384, e0i = base % 384;
            const int gr = rb + row;
            f32x4 lo4 = *(const f32x4*)&low[(size_t)gr * 384 + e0i];
            f32x4 hi4 = *(const f32x4*)&high[(size_t)gr * 384 + e0i];
            ushort4_t s0 = *(const ushort4_t*)&Sg[row * 384 + e0i];
            ushort4_t s1 = *(const ushort4_t*)&Sg[(16 + row) * 384 + e0i];
            ushort4_t fb;
#pragma unroll
            for (int i = 0; i < 4; i++)
                fb[i] = f2bf(w0 * lo4[i] * bf2f(s0[i]) + w1v * hi4[i] * bf2f(s1[i]));
            *(ushort4_t*)&fusedb[(size_t)gr * 384 + e0i] = fb;
        }
    }
}

// ---------------- kernel: qkv projection (32x32x16 MFMA, no A-staging) ----------------
// grid (64, 6) x 256 thr (4 waves: mh x nh); q pre-scaled by 0.125*log2(e)
__global__ __launch_bounds__(256) void k_qkv(
    const ushort_t* __restrict__ fusedb, const ushort_t* __restrict__ wT,
    const float* __restrict__ bqkv,
    ushort_t* __restrict__ qb, ushort_t* __restrict__ kb, ushort_t* __restrict__ vtb) {
    __shared__ float tls[4][32][40];
    const int t = threadIdx.x;
    const int w = t >> 6, l = t & 63, ll = l & 31, hf = l >> 5;
    const int mh = w >> 1, nh = w & 1;
    const int rb = blockIdx.x * 64 + mh * 32;
    const int cb = blockIdx.y * 192 + nh * 96;
    const ushort_t* wq = wT + WQKV_OFF;
    f32x16 acc[3];
#pragma unroll
    for (int nt = 0; nt < 3; nt++)
#pragma unroll
        for (int r = 0; r < 16; r++) acc[nt][r] = 0.0f;
    for (int ks = 0; ks < 24; ks++) {
        s16x8 af = *(const s16x8*)&fusedb[(size_t)(rb + ll) * 384 + ks * 16 + hf * 8];
#pragma unroll
        for (int nt = 0; nt < 3; nt++) {
            s16x8 bf = *(const s16x8*)&wq[(size_t)(cb + nt * 32 + ll) * 384 + ks * 16 + hf * 8];
            acc[nt] = __builtin_amdgcn_mfma_f32_32x32x16_bf16(af, bf, acc[nt], 0, 0, 0);
        }
    }
#pragma unroll
    for (int nt = 0; nt < 3; nt++) {
        const int nb = cb + nt * 32;
        const int which = nb / 384, wn = nb % 384;
        const int hb = wn >> 6, d0 = wn & 63;
        const float bias = bqkv[nb + ll];
        if (which == 2) {
            const int d = d0 + ll;
#pragma unroll
            for (int g2 = 0; g2 < 4; g2++) {
                ushort4_t u4;
#pragma unroll
                for (int i2 = 0; i2 < 4; i2++) u4[i2] = f2bf(acc[nt][g2 * 4 + i2] + bias);
                *(ushort4_t*)&vtb[((size_t)(hb * 64 + d)) * Nn + rb + 8 * g2 + 4 * hf] = u4;
            }
        } else {
            const float sc = (which == 0) ? 0.18033688f : 1.0f;  // 0.125*log2(e) on q
#pragma unroll
            for (int r = 0; r < 16; r++) tls[w][CROW(r, hf)][ll] = (acc[nt][r] + bias) * sc;
            ushort_t* dst = which ? kb : qb;
            const int row2 = l >> 1, sg = l & 1;
            union { ushort_t us[16]; s16x8 v[2]; } u;
#pragma unroll
            for (int j = 0; j < 16; j++) u.us[j] = f2bf(tls[w][row2][sg * 16 + j]);
            size_t base = ((size_t)hb * Nn + rb + row2) * 64 + d0 + sg * 16;
            *(s16x8*)&dst[base] = u.v[0];
            *(s16x8*)&dst[base + 8] = u.v[1];
        }
    }
}

// ---------------- kernel: flash attention, softmax-free, dbuf 2-phase, split-K ----------------
// flat grid 768 (XCD-swizzled) x 256 thr (4 waves x 32 q-rows); KV tile 64; bf16 partials
__global__ __launch_bounds__(256) void k_attn(
    const ushort_t* __restrict__ qb, const ushort_t* __restrict__ kb,
    const ushort_t* __restrict__ vtb, ushort_t* __restrict__ pof,
    float* __restrict__ pml) {
    __shared__ ushort_t Kt[2][4096];
    __shared__ ushort_t Vt[2][4096];
    const int t = threadIdx.x;
    const int wid = t >> 6, l = t & 63, ll = l & 31, hf = l >> 5;
    // XCD-aware decode: 8 XCDs x 3 (h,sp)-pairs x 32 q-tiles
    const int lid = blockIdx.x;
    const int xcd = lid & 7, gi = lid >> 3;
    const int pair = xcd * 3 + (gi >> 5);      // [0,24) = Hh*SPLIT
    const int qt = gi & 31;
    const int h = pair % Hh, sp = pair / Hh;
    const int qrow0 = qt * 128 + wid * 32;
    // loop-invariant staging geometry
    const int srow = t >> 3, scol = (t & 7) * 8;
    const int soff0 = srow * 64 + (scol ^ ((srow & 7) << 3));
    const int srow1 = srow + 32;
    const int soff1 = srow1 * 64 + (scol ^ ((srow1 & 7) << 3));
    const ushort_t* kbase = kb + (size_t)h * Nn * DHh;
    const ushort_t* vbase = vtb + (size_t)h * DHh * Nn;
    const int kst0 = sp * (Nn / SPLIT);
#define NT (Nn / (64 * SPLIT))
    s16x8 kr0, kr1, vr0, vr1;
#define AISSUE(TI) { const int ktb = kst0 + (TI) * 64;                                  \
        kr0 = *(const s16x8*)&kbase[(size_t)(ktb + srow) * DHh + scol];                  \
        kr1 = *(const s16x8*)&kbase[(size_t)(ktb + srow1) * DHh + scol];                 \
        vr0 = *(const s16x8*)&vbase[(size_t)srow * Nn + ktb + scol];                     \
        vr1 = *(const s16x8*)&vbase[(size_t)srow1 * Nn + ktb + scol]; }
#define AWRITE(B) {                                                                      \
        *(s16x8*)&Kt[B][soff0] = kr0; *(s16x8*)&Kt[B][soff1] = kr1;                      \
        *(s16x8*)&Vt[B][soff0] = vr0; *(s16x8*)&Vt[B][soff1] = vr1; }

    s16x8 qf[4];
#pragma unroll
    for (int dc = 0; dc < 4; dc++)
        qf[dc] = *(const s16x8*)&qb[((size_t)h * Nn + qrow0 + ll) * DHh + dc * 16 + hf * 8];
    f32x16 o0, o1;
#pragma unroll
    for (int r = 0; r < 16; r++) { o0[r] = 0.0f; o1[r] = 0.0f; }
    float lsum = 0.0f;
    const int xorl = (ll & 7) << 3;

    AISSUE(0);
    AWRITE(0);
    __syncthreads();
    for (int kt = 0; kt < NT; kt++) {
        const int cur = kt & 1;
        if (kt < NT - 1) AISSUE(kt + 1);            // loads in flight during compute
        const ushort_t* KtC = Kt[cur];
        const ushort_t* VtC = Vt[cur];
        f32x16 s0, s1;
#pragma unroll
        for (int r = 0; r < 16; r++) { s0[r] = 0.0f; s1[r] = 0.0f; }
        __builtin_amdgcn_s_setprio(1);
#pragma unroll
        for (int dc = 0; dc < 4; dc++) {
            const int colE = dc * 16 + hf * 8;
            s16x8 kf0 = *(const s16x8*)&KtC[ll * 64 + (colE ^ xorl)];
            s16x8 kf1 = *(const s16x8*)&KtC[(32 + ll) * 64 + (colE ^ xorl)];
            s0 = __builtin_amdgcn_mfma_f32_32x32x16_bf16(kf0, qf[dc], s0, 0, 0, 0);
            s1 = __builtin_amdgcn_mfma_f32_32x32x16_bf16(kf1, qf[dc], s1, 0, 0, 0);
        }
        __builtin_amdgcn_s_setprio(0);
        // softmax-free: P = exp2(s); per-lane lsum (cross-half reduce deferred)
#pragma unroll
        for (int r = 0; r < 16; r++) { s0[r] = exp2f(s0[r]); lsum += s0[r]; }
#pragma unroll
        for (int r = 0; r < 16; r++) { s1[r] = exp2f(s1[r]); lsum += s1[r]; }
        // P^T fragments in-register: 2 shuffles per ks
#pragma unroll
        for (int ks = 0; ks < 4; ks++) {
            const f32x16 S = (ks < 2) ? s0 : s1;
            const int b = (ks & 1) * 8;
            unsigned int t1 = cvtpk(S[b + 0], S[b + 1]);
            unsigned int t3 = cvtpk(S[b + 2], S[b + 3]);
            unsigned int t2 = cvtpk(S[b + 4], S[b + 5]);
            unsigned int t4 = cvtpk(S[b + 6], S[b + 7]);
            unsigned int x = __shfl_xor(hf ? t1 : t2, 32, 64);
            unsigned int y = __shfl_xor(hf ? t3 : t4, 32, 64);
            union { unsigned int uw[4]; s16x8 v; } u;
            u.uw[0] = hf ? x : t1;
            u.uw[1] = hf ? y : t3;
            u.uw[2] = hf ? t2 : x;
            u.uw[3] = hf ? t4 : y;
            const int colE = ks * 16 + hf * 8;
            s16x8 vf0 = *(const s16x8*)&VtC[ll * 64 + (colE ^ xorl)];
            s16x8 vf1 = *(const s16x8*)&VtC[(32 + ll) * 64 + (colE ^ xorl)];
            o0 = __builtin_amdgcn_mfma_f32_32x32x16_bf16(vf0, u.v, o0, 0, 0, 0);
            o1 = __builtin_amdgcn_mfma_f32_32x32x16_bf16(vf1, u.v, o1, 0, 0, 0);
        }
        __syncthreads();                           // all waves done reading buf[cur]
        if (kt < NT - 1) {
            AWRITE(cur ^ 1);                       // overwrite the other buffer
            __syncthreads();                       // writes visible before next compute
        }
    }
    lsum += __shfl_xor(lsum, 32, 64);
#pragma unroll
    for (int r = 0; r < 16; r++) {
        const int d_a = CROW(r, hf), d_b = 32 + CROW(r, hf);
        pof[((size_t)(sp * Ee + h * 64 + d_a)) * Nn + qrow0 + ll] = f2bf(o0[r]);
        pof[((size_t)(sp * Ee + h * 64 + d_b)) * Nn + qrow0 + ll] = f2bf(o1[r]);
    }
    if (hf == 0)
        pml[((size_t)sp * Hh + h) * Nn + qrow0 + ll] = lsum;
#undef AISSUE
#undef AWRITE
#undef NT
}

// ---------------- kernel: split-K merge (uniform weights) -> ctx bf16 [N][E] ----------------
// grid (64, 4) x 256; block = 64 q-rows x 96-col quarter
__global__ __launch_bounds__(256) void k_merge(
    const ushort_t* __restrict__ pof, const float* __restrict__ pml,
    ushort_t* __restrict__ ctxb) {
    __shared__ float lsums[SPLIT][Hh][64];
    __shared__ float dinv[Hh][64];
    __shared__ ushort_t tile[64][96];
    const int t = threadIdx.x;
    const int qb0 = blockIdx.x * 64;
    const int eq = blockIdx.y;
    for (int i = t; i < SPLIT * Hh * 64; i += 256) {
        const int s = i / (Hh * 64), r2 = i % (Hh * 64);
        const int hh = r2 / 64, qq = r2 % 64;
        lsums[s][hh][qq] = pml[((size_t)s * Hh + hh) * Nn + qb0 + qq];
    }
    __syncthreads();
    for (int i = t; i < Hh * 64; i += 256) {
        const int hh = i / 64, qq = i % 64;
        float den = 0.0f;
#pragma unroll
        for (int s = 0; s < SPLIT; s++) den += lsums[s][hh][qq];
        dinv[hh][qq] = 1.0f / den;
    }
    __syncthreads();
    const int qq = t & 63, e0 = t >> 6;
    for (int i = 0; i < 24; i++) {
        const int el = e0 + 4 * i;
        const int e = eq * 96 + el;
        const int hh = e >> 6;
        float acc = 0.0f;
#pragma unroll
        for (int s = 0; s < SPLIT; s++)
            acc += bf2f(pof[((size_t)(s * Ee + e)) * Nn + qb0 + qq]);
        tile[qq][el] = f2bf(acc * dinv[hh][qq]);
    }
    __syncthreads();
    for (int i = t; i < 64 * 12; i += 256) {
        const int q2 = i / 12, sg = i % 12;
        *(s16x8*)&ctxb[((size_t)(qb0 + q2)) * 384 + eq * 96 + sg * 8] =
            *(const s16x8*)&tile[q2][sg * 8];
    }
}

// ---------------- kernel: out-proj + bf16 residual + LayerNorm + weighted partials ----------------
// grid 256 x 256 thr (4 waves); 16 rows/block; 16x16x32 MFMA, 6 chains/wave
__global__ __launch_bounds__(256) void k_oln(
    const ushort_t* __restrict__ ctxb, const ushort_t* __restrict__ wT,
    const float* __restrict__ bo, const ushort_t* __restrict__ fusedb,
    const float* __restrict__ lng, const float* __restrict__ lnb,
    const float* __restrict__ rw, float* __restrict__ part) {
    __shared__ float xs[16][388];
    __shared__ float stats[16][2];
    const int t = threadIdx.x;
    const int w = t >> 6, l = t & 63, l15 = l & 15, g4 = l >> 4;
    const int rb = blockIdx.x * 16;
    const ushort_t* woT = wT + WO_OFF;
    f32x4 oA[6];
#pragma unroll
    for (int nt = 0; nt < 6; nt++) oA[nt] = (f32x4){0.f, 0.f, 0.f, 0.f};
    for (int ks = 0; ks < 12; ks++) {
        s16x8 af = *(const s16x8*)&ctxb[(size_t)(rb + l15) * 384 + ks * 32 + g4 * 8];
#pragma unroll
        for (int nt = 0; nt < 6; nt++) {
            s16x8 bf = *(const s16x8*)&woT[(size_t)(w * 96 + nt * 16 + l15) * 384 + ks * 32 + g4 * 8];
            oA[nt] = __builtin_amdgcn_mfma_f32_16x16x32_bf16(af, bf, oA[nt], 0, 0, 0);
        }
    }
#pragma unroll
    for (int nt = 0; nt < 6; nt++) {
        const int col = w * 96 + nt * 16 + l15;
        const float bias = bo[col];
#pragma unroll
        for (int r = 0; r < 4; r++) {
            const int row = g4 * 4 + r;
            xs[row][col] = oA[nt][r] + bias + bf2f(fusedb[(size_t)(rb + row) * 384 + col]);
        }
    }
    __syncthreads();
    {
        const int row = t >> 4, j = t & 15;
        float s1 = 0.0f, s2 = 0.0f;
        for (int i = 0; i < 24; i++) {
            const float x = xs[row][j + 16 * i];
            s1 += x;
            s2 += x * x;
        }
#pragma unroll
        for (int off = 1; off < 16; off <<= 1) {
            s1 += __shfl_xor(s1, off, 64);
            s2 += __shfl_xor(s2, off, 64);
        }
        if (j == 0) {
            const float mu = s1 * (1.0f / Ee);
            const float var = s2 * (1.0f / Ee) - mu * mu;
            stats[row][0] = mu;
            stats[row][1] = rsqrtf(var + 1e-5f);
        }
    }
    __syncthreads();
    for (int c = t; c < 384; c += 256) {
        const float gt = lng[c], bb = lnb[c];
        float acc = 0.0f;
        for (int r = 0; r < 16; r++) {
            const float xn = (xs[r][c] - stats[r][0]) * stats[r][1] * gt + bb;
            acc += xn * rw[rb + r];
        }
        part[(size_t)blockIdx.x * Ee + c] = acc;
    }
}

// ---------------- kernel: ordered partial reduce + L2 normalize (winv folded into eps) ----------------
__global__ __launch_bounds__(384) void k_final(const float* __restrict__ part,
                                               const float* __restrict__ rw,
                                               float* __restrict__ outp) {
    __shared__ float red[6], redw[6];
    const int t = threadIdx.x;
    float s = 0.0f;
    for (int b = 0; b < 256; b++) s += part[(size_t)b * Ee + t];
    float wsp = 0.0f;
    for (int i = t; i < Nn; i += 384) wsp += rw[i];
    float q2 = s * s;
#pragma unroll
    for (int off = 32; off > 0; off >>= 1) {
        q2 += __shfl_down(q2, off, 64);
        wsp += __shfl_down(wsp, off, 64);
    }
    const int wid = t >> 6, lane = t & 63;
    if (lane == 0) { red[wid] = q2; redw[wid] = wsp; }
    __syncthreads();
    float tot = 0.0f, wtot = 0.0f;
#pragma unroll
    for (int w = 0; w < 6; w++) { tot += red[w]; wtot += redw[w]; }
    outp[t] = s / (sqrtf(tot) + 1e-8f * wtot);
}

extern "C" void kernel_launch(void* const* d_in, const int* in_sizes, int n_in,
                              void* d_out, int out_size, void* d_ws, size_t ws_size,
                              hipStream_t stream) {
    const float* low  = (const float*)d_in[0];
    const float* high = (const float*)d_in[1];
    const float* rw   = (const float*)d_in[2];
    const float* lw1  = (const float*)d_in[3];
    const float* lb1  = (const float*)d_in[4];
    const float* lw2  = (const float*)d_in[5];
    const float* lb2  = (const float*)d_in[6];
    const float* hw1  = (const float*)d_in[7];
    const float* hb1  = (const float*)d_in[8];
    const float* hw2  = (const float*)d_in[9];
    const float* hb2  = (const float*)d_in[10];
    const float* lf   = (const float*)d_in[11];
    const float* wqkv = (const float*)d_in[12];
    const float* bqkv = (const float*)d_in[13];
    const float* wo   = (const float*)d_in[14];
    const float* bo   = (const float*)d_in[15];
    const float* lng  = (const float*)d_in[16];
    const float* lnb  = (const float*)d_in[17];

    float* ws = (float*)d_ws;
    const size_t NE = (size_t)Nn * Ee;
    float* pml  = ws;                      // SPLIT*Hh*Nn f32 (lsum only)
    float* part = ws + 196608;             // 256*384 f32
    ushort_t* u16base = (ushort_t*)(ws + 294912);
    ushort_t* fusedb = u16base;
    ushort_t* vtb    = u16base + NE;
    ushort_t* qb     = u16base + 2 * NE;
    ushort_t* kb     = u16base + 3 * NE;
    ushort_t* ctxb   = u16base + 4 * NE;
    ushort_t* wT     = u16base + 5 * NE;   // 737280
    ushort_t* pof    = wT + 737280;        // SPLIT*Ee*Nn

    hipLaunchKernelGGL(k_cvt, dim3(512), dim3(256), 0, stream,
                       lw1, hw1, lw2, hw2, wqkv, wo, wT);
    hipLaunchKernelGGL(k_mlp, dim3(256), dim3(256), 0, stream,
                       low, high, lf, wT, lb1, lb2, hb1, hb2, fusedb);
    hipLaunchKernelGGL(k_qkv, dim3(64, 6), dim3(256), 0, stream,
                       fusedb, wT, bqkv, qb, kb, vtb);
    hipLaunchKernelGGL(k_attn, dim3(Hh * SPLIT * 32), dim3(256), 0, stream,
                       qb, kb, vtb, pof, pml);
    hipLaunchKernelGGL(k_merge, dim3(64, 4), dim3(256), 0, stream, pof, pml, ctxb);
    hipLaunchKernelGGL(k_oln, dim3(256), dim3(256), 0, stream,
                       ctxb, wT, bo, fusedb, lng, lnb, rw, part);
    hipLaunchKernelGGL(k_final, dim3(1), dim3(384), 0, stream, part, rw, (float*)d_out);
}